// Round 1
// baseline (3434.855 us; speedup 1.0000x reference)
//
#include <hip/hip_runtime.h>
#include <math.h>

#define BB 8
#define TT 24
#define WWIN 48
#define DD 512
#define HH 8
#define EE 64
#define DI 1024
#define SS 64
#define RR 32
#define KCONV 4
#define DFF 2048
#define LL (TT*WWIN)      // 1152
#define ML (BB*LL)        // 9216

// ---------------------------------------------------------------------------
// Generic GEMM: C[m,n] = act( sum_k A[m,k]*W[n,k] + bias[n] ) + res[m,n]
// A: [M, lda] row-major (uses first K cols), W: [N, K] row-major (torch Linear)
// act: 0=none, 1=gelu(exact), 2=softplus
// 64x64 tile, TK=16, 256 threads, 4x4 microtile, float4 LDS fragment reads.
// ---------------------------------------------------------------------------
__global__ __launch_bounds__(256) void gemm_bt(
    const float* __restrict__ A, int lda,
    const float* __restrict__ W,
    const float* __restrict__ bias,
    const float* __restrict__ res,
    float* __restrict__ C,
    int M, int N, int K, int act)
{
  __shared__ __align__(16) float As[16][68];
  __shared__ __align__(16) float Ws[16][68];
  const int tid = threadIdx.x;
  const int tx = tid & 15, ty = tid >> 4;
  const int m0 = blockIdx.y << 6, n0 = blockIdx.x << 6;
  const int lk = tid & 15;       // k within K-tile
  const int lr = tid >> 4;       // 0..15 row group
  float acc[4][4] = {};
  const int KT = K >> 4;         // K always a multiple of 16 here
  for (int kt = 0; kt < KT; ++kt) {
    const int k0 = kt << 4;
    __syncthreads();
#pragma unroll
    for (int r = 0; r < 4; ++r) {
      const int mm = lr + (r << 4);
      As[lk][mm] = A[(size_t)(m0 + mm) * lda + k0 + lk];
      Ws[lk][mm] = (n0 + mm < N) ? W[(size_t)(n0 + mm) * K + k0 + lk] : 0.f;
    }
    __syncthreads();
#pragma unroll
    for (int kk = 0; kk < 16; ++kk) {
      const float4 a4 = *(const float4*)&As[kk][ty << 2];
      const float4 b4 = *(const float4*)&Ws[kk][tx << 2];
      const float a[4] = {a4.x, a4.y, a4.z, a4.w};
      const float b[4] = {b4.x, b4.y, b4.z, b4.w};
#pragma unroll
      for (int i = 0; i < 4; ++i)
#pragma unroll
        for (int j = 0; j < 4; ++j)
          acc[i][j] = fmaf(a[i], b[j], acc[i][j]);
    }
  }
#pragma unroll
  for (int i = 0; i < 4; ++i) {
    const int m = m0 + (ty << 2) + i;
#pragma unroll
    for (int j = 0; j < 4; ++j) {
      const int n = n0 + (tx << 2) + j;
      if (n < N) {
        float v = acc[i][j];
        if (bias) v += bias[n];
        if (act == 1) v = 0.5f * v * (1.f + erff(v * 0.70710678118654752f));
        else if (act == 2) v = fmaxf(v, 0.f) + log1pf(expf(-fabsf(v)));
        if (res) v += res[(size_t)m * N + n];
        C[(size_t)m * N + n] = v;
      }
    }
  }
}

// ---------------------------------------------------------------------------
// Causal depthwise conv1d (kernel 4) + SiLU. upre: [B*L, DI] -> uout same.
// ---------------------------------------------------------------------------
__global__ __launch_bounds__(256) void conv_silu(
    const float* __restrict__ upre, const float* __restrict__ cw,
    const float* __restrict__ cb, float* __restrict__ uout)
{
  const size_t idx = (size_t)blockIdx.x * 256 + threadIdx.x;
  if (idx >= (size_t)ML * DI) return;
  const int di = (int)(idx & (DI - 1));
  const int bt = (int)(idx >> 10);
  const int t = bt % LL;
  float acc = cb[di];
#pragma unroll
  for (int k = 0; k < KCONV; ++k) {
    const int tt = t - (KCONV - 1) + k;
    if (tt >= 0)
      acc = fmaf(upre[idx - (size_t)(KCONV - 1 - k) * DI], cw[di * KCONV + k], acc);
  }
  uout[idx] = acc / (1.f + __expf(-acc));
}

// ---------------------------------------------------------------------------
// Selective-scan: one wave per (b, di); lane = state s. Fuses +u*D and
// *silu(z) gating into the per-step epilogue.
// ---------------------------------------------------------------------------
__global__ __launch_bounds__(256) void scan_kernel(
    const float* __restrict__ delta, const float* __restrict__ u,
    const float* __restrict__ z, const float* __restrict__ xdbc,
    const float* __restrict__ A_log, const float* __restrict__ D_ssm,
    float* __restrict__ y)
{
  const int w = (int)((blockIdx.x * blockDim.x + threadIdx.x) >> 6);
  const int lane = threadIdx.x & 63;
  const int b = w >> 10;            // DI = 1024 channels per batch
  const int di = w & (DI - 1);
  const float Aval = -__expf(A_log[di * SS + lane]);
  const float Dd = D_ssm[di];
  const size_t rb = (size_t)b * LL;
  const float* dp = delta + rb * DI + di;
  const float* up = u + rb * DI + di;
  const float* zp = z + rb * DI + di;
  const float* bp = xdbc + rb * (RR + 2 * SS) + RR + lane;
  const float* cp = bp + SS;
  float* yp = y + rb * DI + di;
  float h = 0.f;
  for (int t = 0; t < LL; ++t) {
    const float dt = dp[(size_t)t * DI];
    const float ut = up[(size_t)t * DI];
    const float Bv = bp[(size_t)t * (RR + 2 * SS)];
    const float Cv = cp[(size_t)t * (RR + 2 * SS)];
    h = fmaf(h, __expf(dt * Aval), dt * ut * Bv);
    float v = h * Cv;
#pragma unroll
    for (int off = 32; off; off >>= 1) v += __shfl_xor(v, off, 64);
    if (lane == 0) {
      const float zt = zp[(size_t)t * DI];
      yp[(size_t)t * DI] = (v + ut * Dd) * (zt / (1.f + __expf(-zt)));
    }
  }
}

// ---------------------------------------------------------------------------
// Flash-style attention, fp32. One block per (b, h, 64-query tile).
// K-tile and P-tile share one LDS buffer. Scale folded into Q load.
// ---------------------------------------------------------------------------
__global__ __launch_bounds__(256) void attn_kernel(
    const float* __restrict__ q, const float* __restrict__ k,
    const float* __restrict__ v, float* __restrict__ o)
{
  __shared__ __align__(16) float Qs[64][68];
  __shared__ __align__(16) float KPs[64][68];   // K tile, then P tile
  __shared__ __align__(16) float Vs[64][68];
  const int tid = threadIdx.x;
  const int tx = tid & 15, ty = tid >> 4;
  const int bh = blockIdx.y;
  const int b = bh >> 3, hh = bh & 7;           // H = 8
  const int q0 = blockIdx.x << 6;
  const size_t base = (size_t)b * LL * DD + (size_t)hh * EE;

  for (int idx = tid; idx < 64 * 64; idx += 256) {
    const int qi = idx >> 6, e = idx & 63;
    Qs[qi][e] = q[base + (size_t)(q0 + qi) * DD + e] * 0.125f;  // 1/sqrt(64)
  }
  float m_i[4], l_i[4], acc[4][4];
#pragma unroll
  for (int i = 0; i < 4; ++i) {
    m_i[i] = -INFINITY; l_i[i] = 0.f;
#pragma unroll
    for (int j = 0; j < 4; ++j) acc[i][j] = 0.f;
  }

  for (int kt = 0; kt < LL / 64; ++kt) {
    __syncthreads();                      // prev-iter KPs/Vs reads done
    const int k0 = kt << 6;
    for (int idx = tid; idx < 64 * 64; idx += 256) {
      const int ki = idx >> 6, e = idx & 63;
      KPs[ki][e] = k[base + (size_t)(k0 + ki) * DD + e];
      Vs[ki][e]  = v[base + (size_t)(k0 + ki) * DD + e];
    }
    __syncthreads();

    float s[4][4] = {};
#pragma unroll 4
    for (int e4 = 0; e4 < 16; ++e4) {
      float qf[4][4], kf[4][4];
#pragma unroll
      for (int i = 0; i < 4; ++i) {
        const float4 a4 = *(const float4*)&Qs[(ty << 2) + i][e4 << 2];
        qf[i][0] = a4.x; qf[i][1] = a4.y; qf[i][2] = a4.z; qf[i][3] = a4.w;
      }
#pragma unroll
      for (int j = 0; j < 4; ++j) {
        const float4 b4 = *(const float4*)&KPs[(tx << 2) + j][e4 << 2];
        kf[j][0] = b4.x; kf[j][1] = b4.y; kf[j][2] = b4.z; kf[j][3] = b4.w;
      }
#pragma unroll
      for (int i = 0; i < 4; ++i)
#pragma unroll
        for (int j = 0; j < 4; ++j)
#pragma unroll
          for (int c = 0; c < 4; ++c)
            s[i][j] = fmaf(qf[i][c], kf[j][c], s[i][j]);
    }

    // online softmax (per-query reduction across the 16 tx lanes)
    float p[4][4], alpha[4];
#pragma unroll
    for (int i = 0; i < 4; ++i) {
      float mt = fmaxf(fmaxf(s[i][0], s[i][1]), fmaxf(s[i][2], s[i][3]));
#pragma unroll
      for (int off = 1; off < 16; off <<= 1) mt = fmaxf(mt, __shfl_xor(mt, off, 16));
      const float mn = fmaxf(m_i[i], mt);
      alpha[i] = __expf(m_i[i] - mn);
      m_i[i] = mn;
      float rs = 0.f;
#pragma unroll
      for (int j = 0; j < 4; ++j) { p[i][j] = __expf(s[i][j] - mn); rs += p[i][j]; }
#pragma unroll
      for (int off = 1; off < 16; off <<= 1) rs += __shfl_xor(rs, off, 16);
      l_i[i] = l_i[i] * alpha[i] + rs;
    }

    __syncthreads();                      // everyone done reading KPs as K
#pragma unroll
    for (int i = 0; i < 4; ++i)
#pragma unroll
      for (int j = 0; j < 4; ++j)
        KPs[(ty << 2) + i][(tx << 2) + j] = p[i][j];
    __syncthreads();                      // P visible

#pragma unroll
    for (int i = 0; i < 4; ++i)
#pragma unroll
      for (int j = 0; j < 4; ++j) acc[i][j] *= alpha[i];

#pragma unroll 4
    for (int k4 = 0; k4 < 16; ++k4) {
      float vvf[4][4];
#pragma unroll
      for (int kk = 0; kk < 4; ++kk) {
        const float4 t4 = *(const float4*)&Vs[(k4 << 2) + kk][tx << 2];
        vvf[kk][0] = t4.x; vvf[kk][1] = t4.y; vvf[kk][2] = t4.z; vvf[kk][3] = t4.w;
      }
#pragma unroll
      for (int i = 0; i < 4; ++i) {
        const float4 p4 = *(const float4*)&KPs[(ty << 2) + i][k4 << 2];
        const float pf[4] = {p4.x, p4.y, p4.z, p4.w};
#pragma unroll
        for (int kk = 0; kk < 4; ++kk)
#pragma unroll
          for (int j = 0; j < 4; ++j)
            acc[i][j] = fmaf(pf[kk], vvf[kk][j], acc[i][j]);
      }
    }
  }

#pragma unroll
  for (int i = 0; i < 4; ++i) {
    const float inv = 1.f / l_i[i];
#pragma unroll
    for (int j = 0; j < 4; ++j)
      o[base + (size_t)(q0 + (ty << 2) + i) * DD + (tx << 2) + j] = acc[i][j] * inv;
  }
}

// ---------------------------------------------------------------------------
// h = LN1(xf + attn + mamba); hn = LN2(h). One row (512) per 256-thread block.
// ---------------------------------------------------------------------------
__device__ __forceinline__ float block_sum512(float val, float* sm)
{
#pragma unroll
  for (int off = 32; off; off >>= 1) val += __shfl_xor(val, off, 64);
  const int wid = threadIdx.x >> 6;
  __syncthreads();
  if ((threadIdx.x & 63) == 0) sm[wid] = val;
  __syncthreads();
  return sm[0] + sm[1] + sm[2] + sm[3];
}

__global__ __launch_bounds__(256) void ln_fused(
    const float* __restrict__ xf, const float* __restrict__ ao,
    const float* __restrict__ mo,
    const float* __restrict__ g1, const float* __restrict__ b1,
    const float* __restrict__ g2, const float* __restrict__ b2,
    float* __restrict__ hout, float* __restrict__ hnout)
{
  __shared__ float sm[4];
  const size_t base = (size_t)blockIdx.x * DD;
  const int t = threadIdx.x;
  const float v0 = xf[base + t] + ao[base + t] + mo[base + t];
  const float v1 = xf[base + 256 + t] + ao[base + 256 + t] + mo[base + 256 + t];
  const float mean = block_sum512(v0 + v1, sm) * (1.f / DD);
  const float d0 = v0 - mean, d1 = v1 - mean;
  const float var = block_sum512(d0 * d0 + d1 * d1, sm) * (1.f / DD);
  const float rstd = rsqrtf(var + 1e-5f);
  const float h0 = d0 * rstd * g1[t] + b1[t];
  const float h1 = d1 * rstd * g1[t + 256] + b1[t + 256];
  hout[base + t] = h0;
  hout[base + 256 + t] = h1;
  const float mean2 = block_sum512(h0 + h1, sm) * (1.f / DD);
  const float e0 = h0 - mean2, e1 = h1 - mean2;
  const float var2 = block_sum512(e0 * e0 + e1 * e1, sm) * (1.f / DD);
  const float rstd2 = rsqrtf(var2 + 1e-6f);
  hnout[base + t] = e0 * rstd2 * g2[t] + b2[t];
  hnout[base + 256 + t] = e1 * rstd2 * g2[t + 256] + b2[t + 256];
}

// ---------------------------------------------------------------------------
extern "C" void kernel_launch(void* const* d_in, const int* in_sizes, int n_in,
                              void* d_out, int out_size, void* d_ws, size_t ws_size,
                              hipStream_t stream)
{
  const float* x         = (const float*)d_in[0];
  // d_in[1] = slf_attn_mask: all-False, ignored
  const float* Wq        = (const float*)d_in[2];
  const float* bq        = (const float*)d_in[3];
  const float* Wk        = (const float*)d_in[4];
  const float* bk        = (const float*)d_in[5];
  const float* Wv        = (const float*)d_in[6];
  const float* bv        = (const float*)d_in[7];
  const float* Wo        = (const float*)d_in[8];
  const float* bo        = (const float*)d_in[9];
  const float* in_proj_w = (const float*)d_in[10];
  const float* conv_w    = (const float*)d_in[11];
  const float* conv_b    = (const float*)d_in[12];
  const float* x_proj_w  = (const float*)d_in[13];
  const float* dt_proj_w = (const float*)d_in[14];
  const float* dt_proj_b = (const float*)d_in[15];
  const float* A_log     = (const float*)d_in[16];
  const float* D_ssm     = (const float*)d_in[17];
  const float* out_proj_w= (const float*)d_in[18];
  const float* ln1_g     = (const float*)d_in[19];
  const float* ln1_b     = (const float*)d_in[20];
  const float* ffn_w1    = (const float*)d_in[21];
  const float* ffn_b1    = (const float*)d_in[22];
  const float* ffn_w2    = (const float*)d_in[23];
  const float* ffn_b2    = (const float*)d_in[24];
  const float* ln2_g     = (const float*)d_in[25];
  const float* ln2_b     = (const float*)d_in[26];
  float* out = (float*)d_out;

  // ---- workspace layout (phase-based reuse), peak 39,223,296 floats ≈ 157 MB
  float* ws = (float*)d_ws;
  const size_t SZ_MLDI = (size_t)ML * DI;   // 9,437,184
  const size_t SZ_MLD  = (size_t)ML * DD;   // 4,718,592
  float* upre  = ws;                        // [ML, DI]  u pre-conv | later: delta, mamba_out, hn
  float* zbuf  = upre + SZ_MLDI;            // [ML, DI]  z          | later: q, k / ffbuf
  float* ubuf  = zbuf + SZ_MLDI;            // [ML, DI]  conv(u)   | later: v, attn
  float* xdbc  = ubuf + SZ_MLDI;            // [ML, 160]
  float* ybuf  = xdbc + (size_t)ML * (RR + 2 * SS);   // [ML, DI] | later: ao, h
  float* deltab = upre;
  float* mambab = upre;
  float* hnbuf  = upre + SZ_MLD;
  float* qbuf   = zbuf;
  float* kbuf   = zbuf + SZ_MLD;
  float* vbuf   = ubuf;
  float* attnb  = ubuf + SZ_MLD;
  float* ffbuf  = zbuf;                     // spans zbuf+ubuf (18.9M floats)
  float* aobuf  = ybuf;
  float* hbuf   = ybuf + SZ_MLD;

  const dim3 thr(256);
#define GEMM(Aptr, lda_, Wptr, Bptr, Rptr, Cptr, N_, K_, act_) \
  gemm_bt<<<dim3(((N_) + 63) / 64, ML / 64), thr, 0, stream>>>( \
      Aptr, lda_, Wptr, Bptr, Rptr, Cptr, ML, N_, K_, act_)

  // ---- mamba branch
  GEMM(x, DD, in_proj_w, nullptr, nullptr, upre, DI, DD, 0);                 // u pre
  GEMM(x, DD, in_proj_w + (size_t)DI * DD, nullptr, nullptr, zbuf, DI, DD, 0); // z
  conv_silu<<<dim3((unsigned)(((size_t)ML * DI + 255) / 256)), thr, 0, stream>>>(
      upre, conv_w, conv_b, ubuf);
  GEMM(ubuf, DI, x_proj_w, nullptr, nullptr, xdbc, RR + 2 * SS, DI, 0);      // x_proj
  GEMM(xdbc, RR + 2 * SS, dt_proj_w, dt_proj_b, nullptr, deltab, DI, RR, 2); // delta (softplus)
  scan_kernel<<<dim3((BB * DI) / 4), thr, 0, stream>>>(
      deltab, ubuf, zbuf, xdbc, A_log, D_ssm, ybuf);                         // gated y
  GEMM(ybuf, DI, out_proj_w, nullptr, nullptr, mambab, DD, DI, 0);           // mamba out

  // ---- attention branch
  GEMM(x, DD, Wq, bq, nullptr, qbuf, DD, DD, 0);
  GEMM(x, DD, Wk, bk, nullptr, kbuf, DD, DD, 0);
  GEMM(x, DD, Wv, bv, nullptr, vbuf, DD, DD, 0);
  attn_kernel<<<dim3(LL / 64, BB * HH), thr, 0, stream>>>(qbuf, kbuf, vbuf, attnb);
  GEMM(attnb, DD, Wo, bo, nullptr, aobuf, DD, DD, 0);

  // ---- combine + LN1 + LN2
  ln_fused<<<dim3(ML), thr, 0, stream>>>(x, aobuf, mambab, ln1_g, ln1_b,
                                         ln2_g, ln2_b, hbuf, hnbuf);

  // ---- FFN (gelu fused into GEMM1, residual fused into GEMM2)
  GEMM(hnbuf, DD, ffn_w1, ffn_b1, nullptr, ffbuf, DFF, DD, 1);
  GEMM(ffbuf, DFF, ffn_w2, ffn_b2, hbuf, out, DD, DFF, 0);
#undef GEMM
}

// Round 2
// 2952.023 us; speedup vs baseline: 1.1636x; 1.1636x over previous
//
#include <hip/hip_runtime.h>
#include <math.h>

#define BB 8
#define TT 24
#define WWIN 48
#define DD 512
#define HH 8
#define EE 64
#define DI 1024
#define SS 64
#define RR 32
#define KCONV 4
#define DFF 2048
#define LL (TT*WWIN)      // 1152
#define ML (BB*LL)        // 9216
#define XS (RR + 2*SS)    // 160

// ---------------------------------------------------------------------------
// Generic GEMM: C[m,n] = act( sum_k A[m,k]*W[n,k] + bias[n] ) + res[m,n]
// ---------------------------------------------------------------------------
__global__ __launch_bounds__(256) void gemm_bt(
    const float* __restrict__ A, int lda,
    const float* __restrict__ W,
    const float* __restrict__ bias,
    const float* __restrict__ res,
    float* __restrict__ C,
    int M, int N, int K, int act)
{
  __shared__ __align__(16) float As[16][68];
  __shared__ __align__(16) float Ws[16][68];
  const int tid = threadIdx.x;
  const int tx = tid & 15, ty = tid >> 4;
  const int m0 = blockIdx.y << 6, n0 = blockIdx.x << 6;
  const int lk = tid & 15;
  const int lr = tid >> 4;
  float acc[4][4] = {};
  const int KT = K >> 4;
  for (int kt = 0; kt < KT; ++kt) {
    const int k0 = kt << 4;
    __syncthreads();
#pragma unroll
    for (int r = 0; r < 4; ++r) {
      const int mm = lr + (r << 4);
      As[lk][mm] = A[(size_t)(m0 + mm) * lda + k0 + lk];
      Ws[lk][mm] = (n0 + mm < N) ? W[(size_t)(n0 + mm) * K + k0 + lk] : 0.f;
    }
    __syncthreads();
#pragma unroll
    for (int kk = 0; kk < 16; ++kk) {
      const float4 a4 = *(const float4*)&As[kk][ty << 2];
      const float4 b4 = *(const float4*)&Ws[kk][tx << 2];
      const float a[4] = {a4.x, a4.y, a4.z, a4.w};
      const float b[4] = {b4.x, b4.y, b4.z, b4.w};
#pragma unroll
      for (int i = 0; i < 4; ++i)
#pragma unroll
        for (int j = 0; j < 4; ++j)
          acc[i][j] = fmaf(a[i], b[j], acc[i][j]);
    }
  }
#pragma unroll
  for (int i = 0; i < 4; ++i) {
    const int m = m0 + (ty << 2) + i;
#pragma unroll
    for (int j = 0; j < 4; ++j) {
      const int n = n0 + (tx << 2) + j;
      if (n < N) {
        float v = acc[i][j];
        if (bias) v += bias[n];
        if (act == 1) v = 0.5f * v * (1.f + erff(v * 0.70710678118654752f));
        else if (act == 2) v = fmaxf(v, 0.f) + log1pf(expf(-fabsf(v)));
        if (res) v += res[(size_t)m * N + n];
        C[(size_t)m * N + n] = v;
      }
    }
  }
}

// ---------------------------------------------------------------------------
// Causal depthwise conv1d (kernel 4) + SiLU.
// ---------------------------------------------------------------------------
__global__ __launch_bounds__(256) void conv_silu(
    const float* __restrict__ upre, const float* __restrict__ cw,
    const float* __restrict__ cb, float* __restrict__ uout)
{
  const size_t idx = (size_t)blockIdx.x * 256 + threadIdx.x;
  if (idx >= (size_t)ML * DI) return;
  const int di = (int)(idx & (DI - 1));
  const int bt = (int)(idx >> 10);
  const int t = bt % LL;
  float acc = cb[di];
#pragma unroll
  for (int k = 0; k < KCONV; ++k) {
    const int tt = t - (KCONV - 1) + k;
    if (tt >= 0)
      acc = fmaf(upre[idx - (size_t)(KCONV - 1 - k) * DI], cw[di * KCONV + k], acc);
  }
  uout[idx] = acc / (1.f + __expf(-acc));
}

// ---------------------------------------------------------------------------
// Selective-scan v2: one wave per (b, di); lane = state s.
//  - 8-step double-buffered register tiles (load tile k+1 while computing k)
//  - reduction: 5x immediate ds_swizzle (xor 1,2,4,8,16) + shfl_xor(32)
//  - branch-free gate; y stashed per-lane, one scatter store per 64 steps
// ---------------------------------------------------------------------------
template<int IMM>
__device__ __forceinline__ float swz(float x) {
  return __uint_as_float((unsigned)__builtin_amdgcn_ds_swizzle((int)__float_as_uint(x), IMM));
}

#define SCAN_LOAD(P, t0) { _Pragma("unroll") for (int j = 0; j < 8; ++j) { \
    P##_dt[j] = dp[(size_t)((t0)+j)*DI]; \
    P##_u[j]  = up[(size_t)((t0)+j)*DI]; \
    P##_z[j]  = zp[(size_t)((t0)+j)*DI]; \
    P##_B[j]  = bp[(size_t)((t0)+j)*XS]; \
    P##_C[j]  = cp[(size_t)((t0)+j)*XS]; } }

#define SCAN_STEP(P, j, t) { \
    const float dA = __expf(P##_dt[j] * Aval); \
    const float dtu = P##_dt[j] * P##_u[j]; \
    h = fmaf(h, dA, dtu * P##_B[j]); \
    float v = h * P##_C[j]; \
    v += swz<0x041F>(v); v += swz<0x081F>(v); v += swz<0x101F>(v); \
    v += swz<0x201F>(v); v += swz<0x401F>(v); \
    v += __shfl_xor(v, 32, 64); \
    const float zz = P##_z[j]; \
    const float gate = zz / (1.f + __expf(-zz)); \
    const float yv = (v + P##_u[j] * Dd) * gate; \
    ystash = (((t) & 63) == lane) ? yv : ystash; }

#define SCAN_COMPUTE(P, t0) { \
    _Pragma("unroll") for (int j = 0; j < 8; ++j) SCAN_STEP(P, j, (t0)+j) \
    if ((((t0)+8) & 63) == 0) yp[(size_t)((t0) - 56 + lane) * DI] = ystash; }

__global__ __launch_bounds__(256) void scan_kernel(
    const float* __restrict__ delta, const float* __restrict__ u,
    const float* __restrict__ z, const float* __restrict__ xdbc,
    const float* __restrict__ A_log, const float* __restrict__ D_ssm,
    float* __restrict__ y)
{
  const int w = (int)((blockIdx.x * blockDim.x + threadIdx.x) >> 6);
  const int lane = threadIdx.x & 63;
  const int b = w >> 10;            // DI = 1024 channels per batch
  const int di = w & (DI - 1);
  const float Aval = -__expf(A_log[di * SS + lane]);
  const float Dd = D_ssm[di];
  const size_t rb = (size_t)b * LL;
  const float* __restrict__ dp = delta + rb * DI + di;
  const float* __restrict__ up = u + rb * DI + di;
  const float* __restrict__ zp = z + rb * DI + di;
  const float* __restrict__ bp = xdbc + rb * XS + RR + lane;
  const float* __restrict__ cp = bp + SS;
  float* __restrict__ yp = y + rb * DI + di;

  float h = 0.f, ystash = 0.f;
  float a_dt[8], a_u[8], a_z[8], a_B[8], a_C[8];
  float b_dt[8], b_u[8], b_z[8], b_B[8], b_C[8];

  SCAN_LOAD(a, 0)
  for (int t0 = 0; t0 < LL; t0 += 16) {
    SCAN_LOAD(b, t0 + 8)
    SCAN_COMPUTE(a, t0)
    if (t0 + 16 < LL) SCAN_LOAD(a, t0 + 16)
    SCAN_COMPUTE(b, t0 + 8)
  }
}

// ---------------------------------------------------------------------------
// Flash-style attention, fp32. One block per (b, h, 64-query tile).
// ---------------------------------------------------------------------------
__global__ __launch_bounds__(256) void attn_kernel(
    const float* __restrict__ q, const float* __restrict__ k,
    const float* __restrict__ v, float* __restrict__ o)
{
  __shared__ __align__(16) float Qs[64][68];
  __shared__ __align__(16) float KPs[64][68];
  __shared__ __align__(16) float Vs[64][68];
  const int tid = threadIdx.x;
  const int tx = tid & 15, ty = tid >> 4;
  const int bh = blockIdx.y;
  const int b = bh >> 3, hh = bh & 7;
  const int q0 = blockIdx.x << 6;
  const size_t base = (size_t)b * LL * DD + (size_t)hh * EE;

  for (int idx = tid; idx < 64 * 64; idx += 256) {
    const int qi = idx >> 6, e = idx & 63;
    Qs[qi][e] = q[base + (size_t)(q0 + qi) * DD + e] * 0.125f;
  }
  float m_i[4], l_i[4], acc[4][4];
#pragma unroll
  for (int i = 0; i < 4; ++i) {
    m_i[i] = -INFINITY; l_i[i] = 0.f;
#pragma unroll
    for (int j = 0; j < 4; ++j) acc[i][j] = 0.f;
  }

  for (int kt = 0; kt < LL / 64; ++kt) {
    __syncthreads();
    const int k0 = kt << 6;
    for (int idx = tid; idx < 64 * 64; idx += 256) {
      const int ki = idx >> 6, e = idx & 63;
      KPs[ki][e] = k[base + (size_t)(k0 + ki) * DD + e];
      Vs[ki][e]  = v[base + (size_t)(k0 + ki) * DD + e];
    }
    __syncthreads();

    float s[4][4] = {};
#pragma unroll 4
    for (int e4 = 0; e4 < 16; ++e4) {
      float qf[4][4], kf[4][4];
#pragma unroll
      for (int i = 0; i < 4; ++i) {
        const float4 a4 = *(const float4*)&Qs[(ty << 2) + i][e4 << 2];
        qf[i][0] = a4.x; qf[i][1] = a4.y; qf[i][2] = a4.z; qf[i][3] = a4.w;
      }
#pragma unroll
      for (int j = 0; j < 4; ++j) {
        const float4 b4 = *(const float4*)&KPs[(tx << 2) + j][e4 << 2];
        kf[j][0] = b4.x; kf[j][1] = b4.y; kf[j][2] = b4.z; kf[j][3] = b4.w;
      }
#pragma unroll
      for (int i = 0; i < 4; ++i)
#pragma unroll
        for (int j = 0; j < 4; ++j)
#pragma unroll
          for (int c = 0; c < 4; ++c)
            s[i][j] = fmaf(qf[i][c], kf[j][c], s[i][j]);
    }

    float p[4][4], alpha[4];
#pragma unroll
    for (int i = 0; i < 4; ++i) {
      float mt = fmaxf(fmaxf(s[i][0], s[i][1]), fmaxf(s[i][2], s[i][3]));
#pragma unroll
      for (int off = 1; off < 16; off <<= 1) mt = fmaxf(mt, __shfl_xor(mt, off, 16));
      const float mn = fmaxf(m_i[i], mt);
      alpha[i] = __expf(m_i[i] - mn);
      m_i[i] = mn;
      float rs = 0.f;
#pragma unroll
      for (int j = 0; j < 4; ++j) { p[i][j] = __expf(s[i][j] - mn); rs += p[i][j]; }
#pragma unroll
      for (int off = 1; off < 16; off <<= 1) rs += __shfl_xor(rs, off, 16);
      l_i[i] = l_i[i] * alpha[i] + rs;
    }

    __syncthreads();
#pragma unroll
    for (int i = 0; i < 4; ++i)
#pragma unroll
      for (int j = 0; j < 4; ++j)
        KPs[(ty << 2) + i][(tx << 2) + j] = p[i][j];
    __syncthreads();

#pragma unroll
    for (int i = 0; i < 4; ++i)
#pragma unroll
      for (int j = 0; j < 4; ++j) acc[i][j] *= alpha[i];

#pragma unroll 4
    for (int k4 = 0; k4 < 16; ++k4) {
      float vvf[4][4];
#pragma unroll
      for (int kk = 0; kk < 4; ++kk) {
        const float4 t4 = *(const float4*)&Vs[(k4 << 2) + kk][tx << 2];
        vvf[kk][0] = t4.x; vvf[kk][1] = t4.y; vvf[kk][2] = t4.z; vvf[kk][3] = t4.w;
      }
#pragma unroll
      for (int i = 0; i < 4; ++i) {
        const float4 p4 = *(const float4*)&KPs[(ty << 2) + i][k4 << 2];
        const float pf[4] = {p4.x, p4.y, p4.z, p4.w};
#pragma unroll
        for (int kk = 0; kk < 4; ++kk)
#pragma unroll
          for (int j = 0; j < 4; ++j)
            acc[i][j] = fmaf(pf[kk], vvf[kk][j], acc[i][j]);
      }
    }
  }

#pragma unroll
  for (int i = 0; i < 4; ++i) {
    const float inv = 1.f / l_i[i];
#pragma unroll
    for (int j = 0; j < 4; ++j)
      o[base + (size_t)(q0 + (ty << 2) + i) * DD + (tx << 2) + j] = acc[i][j] * inv;
  }
}

// ---------------------------------------------------------------------------
// h = LN1(xf + attn + mamba); hn = LN2(h). One row (512) per 256-thread block.
// ---------------------------------------------------------------------------
__device__ __forceinline__ float block_sum512(float val, float* sm)
{
#pragma unroll
  for (int off = 32; off; off >>= 1) val += __shfl_xor(val, off, 64);
  const int wid = threadIdx.x >> 6;
  __syncthreads();
  if ((threadIdx.x & 63) == 0) sm[wid] = val;
  __syncthreads();
  return sm[0] + sm[1] + sm[2] + sm[3];
}

__global__ __launch_bounds__(256) void ln_fused(
    const float* __restrict__ xf, const float* __restrict__ ao,
    const float* __restrict__ mo,
    const float* __restrict__ g1, const float* __restrict__ b1,
    const float* __restrict__ g2, const float* __restrict__ b2,
    float* __restrict__ hout, float* __restrict__ hnout)
{
  __shared__ float sm[4];
  const size_t base = (size_t)blockIdx.x * DD;
  const int t = threadIdx.x;
  const float v0 = xf[base + t] + ao[base + t] + mo[base + t];
  const float v1 = xf[base + 256 + t] + ao[base + 256 + t] + mo[base + 256 + t];
  const float mean = block_sum512(v0 + v1, sm) * (1.f / DD);
  const float d0 = v0 - mean, d1 = v1 - mean;
  const float var = block_sum512(d0 * d0 + d1 * d1, sm) * (1.f / DD);
  const float rstd = rsqrtf(var + 1e-5f);
  const float h0 = d0 * rstd * g1[t] + b1[t];
  const float h1 = d1 * rstd * g1[t + 256] + b1[t + 256];
  hout[base + t] = h0;
  hout[base + 256 + t] = h1;
  const float mean2 = block_sum512(h0 + h1, sm) * (1.f / DD);
  const float e0 = h0 - mean2, e1 = h1 - mean2;
  const float var2 = block_sum512(e0 * e0 + e1 * e1, sm) * (1.f / DD);
  const float rstd2 = rsqrtf(var2 + 1e-6f);
  hnout[base + t] = e0 * rstd2 * g2[t] + b2[t];
  hnout[base + 256 + t] = e1 * rstd2 * g2[t + 256] + b2[t + 256];
}

// ---------------------------------------------------------------------------
extern "C" void kernel_launch(void* const* d_in, const int* in_sizes, int n_in,
                              void* d_out, int out_size, void* d_ws, size_t ws_size,
                              hipStream_t stream)
{
  const float* x         = (const float*)d_in[0];
  const float* Wq        = (const float*)d_in[2];
  const float* bq        = (const float*)d_in[3];
  const float* Wk        = (const float*)d_in[4];
  const float* bk        = (const float*)d_in[5];
  const float* Wv        = (const float*)d_in[6];
  const float* bv        = (const float*)d_in[7];
  const float* Wo        = (const float*)d_in[8];
  const float* bo        = (const float*)d_in[9];
  const float* in_proj_w = (const float*)d_in[10];
  const float* conv_w    = (const float*)d_in[11];
  const float* conv_b    = (const float*)d_in[12];
  const float* x_proj_w  = (const float*)d_in[13];
  const float* dt_proj_w = (const float*)d_in[14];
  const float* dt_proj_b = (const float*)d_in[15];
  const float* A_log     = (const float*)d_in[16];
  const float* D_ssm     = (const float*)d_in[17];
  const float* out_proj_w= (const float*)d_in[18];
  const float* ln1_g     = (const float*)d_in[19];
  const float* ln1_b     = (const float*)d_in[20];
  const float* ffn_w1    = (const float*)d_in[21];
  const float* ffn_b1    = (const float*)d_in[22];
  const float* ffn_w2    = (const float*)d_in[23];
  const float* ffn_b2    = (const float*)d_in[24];
  const float* ln2_g     = (const float*)d_in[25];
  const float* ln2_b     = (const float*)d_in[26];
  float* out = (float*)d_out;

  float* ws = (float*)d_ws;
  const size_t SZ_MLDI = (size_t)ML * DI;
  const size_t SZ_MLD  = (size_t)ML * DD;
  float* upre  = ws;
  float* zbuf  = upre + SZ_MLDI;
  float* ubuf  = zbuf + SZ_MLDI;
  float* xdbc  = ubuf + SZ_MLDI;
  float* ybuf  = xdbc + (size_t)ML * XS;
  float* deltab = upre;
  float* mambab = upre;
  float* hnbuf  = upre + SZ_MLD;
  float* qbuf   = zbuf;
  float* kbuf   = zbuf + SZ_MLD;
  float* vbuf   = ubuf;
  float* attnb  = ubuf + SZ_MLD;
  float* ffbuf  = zbuf;
  float* aobuf  = ybuf;
  float* hbuf   = ybuf + SZ_MLD;

  const dim3 thr(256);
#define GEMM(Aptr, lda_, Wptr, Bptr, Rptr, Cptr, N_, K_, act_) \
  gemm_bt<<<dim3(((N_) + 63) / 64, ML / 64), thr, 0, stream>>>( \
      Aptr, lda_, Wptr, Bptr, Rptr, Cptr, ML, N_, K_, act_)

  // ---- mamba branch
  GEMM(x, DD, in_proj_w, nullptr, nullptr, upre, DI, DD, 0);
  GEMM(x, DD, in_proj_w + (size_t)DI * DD, nullptr, nullptr, zbuf, DI, DD, 0);
  conv_silu<<<dim3((unsigned)(((size_t)ML * DI + 255) / 256)), thr, 0, stream>>>(
      upre, conv_w, conv_b, ubuf);
  GEMM(ubuf, DI, x_proj_w, nullptr, nullptr, xdbc, XS, DI, 0);
  GEMM(xdbc, XS, dt_proj_w, dt_proj_b, nullptr, deltab, DI, RR, 2);
  scan_kernel<<<dim3((BB * DI) / 4), thr, 0, stream>>>(
      deltab, ubuf, zbuf, xdbc, A_log, D_ssm, ybuf);
  GEMM(ybuf, DI, out_proj_w, nullptr, nullptr, mambab, DD, DI, 0);

  // ---- attention branch
  GEMM(x, DD, Wq, bq, nullptr, qbuf, DD, DD, 0);
  GEMM(x, DD, Wk, bk, nullptr, kbuf, DD, DD, 0);
  GEMM(x, DD, Wv, bv, nullptr, vbuf, DD, DD, 0);
  attn_kernel<<<dim3(LL / 64, BB * HH), thr, 0, stream>>>(qbuf, kbuf, vbuf, attnb);
  GEMM(attnb, DD, Wo, bo, nullptr, aobuf, DD, DD, 0);

  // ---- combine + LN1 + LN2
  ln_fused<<<dim3(ML), thr, 0, stream>>>(x, aobuf, mambab, ln1_g, ln1_b,
                                         ln2_g, ln2_b, hbuf, hnbuf);

  // ---- FFN
  GEMM(hnbuf, DD, ffn_w1, ffn_b1, nullptr, ffbuf, DFF, DD, 1);
  GEMM(ffbuf, DFF, ffn_w2, ffn_b2, hbuf, out, DD, DFF, 0);
#undef GEMM
}

// Round 3
// 1626.320 us; speedup vs baseline: 2.1120x; 1.8152x over previous
//
#include <hip/hip_runtime.h>
#include <hip/hip_bf16.h>
#include <math.h>

#define BB 8
#define DD 512
#define HH 8
#define EE 64
#define DI 1024
#define SS 64
#define RR 32
#define KCONV 4
#define DFF 2048
#define LL 1152
#define ML (BB*LL)        // 9216
#define XS (RR + 2*SS)    // 160

typedef short bf16x8 __attribute__((ext_vector_type(8)));
typedef float f32x4 __attribute__((ext_vector_type(4)));

#define GLD_LDS(g, l) \
  __builtin_amdgcn_global_load_lds((const __attribute__((address_space(1))) void*)(g), \
                                   (__attribute__((address_space(3))) void*)(l), 16, 0, 0)

// ---------------------------------------------------------------------------
// f32 -> bf16 conversion (vectorized x4; n % 4 == 0 for all our buffers)
// ---------------------------------------------------------------------------
__global__ __launch_bounds__(256) void cvt_bf16(
    const float* __restrict__ s, __hip_bfloat16* __restrict__ d, int n)
{
  const int i = (blockIdx.x * 256 + threadIdx.x) * 4;
  if (i + 3 < n) {
    const float4 v = *(const float4*)(s + i);
    __hip_bfloat16 t[4] = {__float2bfloat16(v.x), __float2bfloat16(v.y),
                           __float2bfloat16(v.z), __float2bfloat16(v.w)};
    *(ushort4*)(d + i) = *(const ushort4*)t;
  } else {
    for (int k = i; k < n; ++k) d[k] = __float2bfloat16(s[k]);
  }
}

// ---------------------------------------------------------------------------
// MFMA GEMM: C[m,n] = act( sum_k A[m,k]*W[n,k] + bias[n] ) + res[m,n]
// A: bf16 [M, lda]; W: bf16 [N(padded to >=gridx*128), K] (ldw == K).
// 128x128 tile, BK=32, 256 thr = 4 waves (2x2 of 64x64), 16x16x32 bf16 MFMA.
// act: 0 none, 1 gelu(exact), 2 softplus. out_bf16: C is __hip_bfloat16*.
// ---------------------------------------------------------------------------
__global__ __launch_bounds__(256) void gemm_mfma(
    const __hip_bfloat16* __restrict__ A, int lda,
    const __hip_bfloat16* __restrict__ W,
    const float* __restrict__ bias,
    const float* __restrict__ res,
    void* __restrict__ Cv,
    int M, int N, int K, int act, int out_bf16)
{
  __shared__ __align__(16) __hip_bfloat16 As[128 * 32];
  __shared__ __align__(16) __hip_bfloat16 Ws[128 * 32];
  const int tid = threadIdx.x;
  const int wid = tid >> 6, lane = tid & 63;
  const int wr = wid >> 1, wc = wid & 1;
  const int m0 = blockIdx.y << 7, n0 = blockIdx.x << 7;
  const int r1 = tid >> 2;              // 0..63 staging row
  const int c1 = (tid & 3) << 3;        // k-chunk * 8

  const __hip_bfloat16* ga0 = A + (size_t)(m0 + r1) * lda + c1;
  const __hip_bfloat16* ga1 = A + (size_t)(m0 + 64 + r1) * lda + c1;
  const __hip_bfloat16* gw0 = W + (size_t)(n0 + r1) * K + c1;
  const __hip_bfloat16* gw1 = W + (size_t)(n0 + 64 + r1) * K + c1;
  char* lA0 = (char*)As + wid * 1024;
  char* lA1 = lA0 + 4096;
  char* lW0 = (char*)Ws + wid * 1024;
  char* lW1 = lW0 + 4096;

  f32x4 acc[4][4];
#pragma unroll
  for (int i = 0; i < 4; ++i)
#pragma unroll
    for (int j = 0; j < 4; ++j) acc[i][j] = (f32x4){0.f, 0.f, 0.f, 0.f};

  const int fm = lane & 15;
  const int q8 = (lane >> 4) << 3;

  for (int kt = 0; kt < K; kt += 32) {
    __syncthreads();
    GLD_LDS(ga0, lA0); GLD_LDS(ga1, lA1);
    GLD_LDS(gw0, lW0); GLD_LDS(gw1, lW1);
    ga0 += 32; ga1 += 32; gw0 += 32; gw1 += 32;
    __syncthreads();

    bf16x8 af[4], wf[4];
#pragma unroll
    for (int i = 0; i < 4; ++i)
      af[i] = *(const bf16x8*)((const short*)As + (wr * 64 + i * 16 + fm) * 32 + q8);
#pragma unroll
    for (int j = 0; j < 4; ++j)
      wf[j] = *(const bf16x8*)((const short*)Ws + (wc * 64 + j * 16 + fm) * 32 + q8);
#pragma unroll
    for (int i = 0; i < 4; ++i)
#pragma unroll
      for (int j = 0; j < 4; ++j)
        acc[i][j] = __builtin_amdgcn_mfma_f32_16x16x32_bf16(af[i], wf[j], acc[i][j], 0, 0, 0);
  }

  // epilogue: C/D layout col = lane&15, row = (lane>>4)*4 + r
  const int rquad = (lane >> 4) << 2;
#pragma unroll
  for (int j = 0; j < 4; ++j) {
    const int n = n0 + wc * 64 + j * 16 + fm;
    if (n < N) {
      const float bv = bias ? bias[n] : 0.f;
#pragma unroll
      for (int i = 0; i < 4; ++i) {
        const int mb = m0 + wr * 64 + i * 16 + rquad;
#pragma unroll
        for (int r = 0; r < 4; ++r) {
          const int m = mb + r;
          float v = acc[i][j][r] + bv;
          if (act == 1) v = 0.5f * v * (1.f + erff(v * 0.70710678118654752f));
          else if (act == 2) v = fmaxf(v, 0.f) + log1pf(expf(-fabsf(v)));
          const size_t off = (size_t)m * N + n;
          if (res) v += res[off];
          if (out_bf16) ((__hip_bfloat16*)Cv)[off] = __float2bfloat16(v);
          else ((float*)Cv)[off] = v;
        }
      }
    }
  }
}

// ---------------------------------------------------------------------------
// Causal depthwise conv1d (kernel 4) + SiLU, bf16 in/out.
// ---------------------------------------------------------------------------
__global__ __launch_bounds__(256) void conv_silu(
    const __hip_bfloat16* __restrict__ upre, const float* __restrict__ cw,
    const float* __restrict__ cb, __hip_bfloat16* __restrict__ uout)
{
  const size_t idx = (size_t)blockIdx.x * 256 + threadIdx.x;
  if (idx >= (size_t)ML * DI) return;
  const int di = (int)(idx & (DI - 1));
  const int t = (int)((idx >> 10) % LL);
  float acc = cb[di];
#pragma unroll
  for (int k = 0; k < KCONV; ++k) {
    if (t - (KCONV - 1) + k >= 0)
      acc = fmaf((float)upre[idx - (size_t)(KCONV - 1 - k) * DI], cw[di * KCONV + k], acc);
  }
  uout[idx] = __float2bfloat16(acc / (1.f + __expf(-acc)));
}

// ---------------------------------------------------------------------------
// Selective-scan v3: one wave per (b, di); lane = state s.
//  - 4-step double-buffered tiles, VGPR<=64 target (8 waves/SIMD)
//  - gate/D-term/z moved to once-per-64-step frame epilogue (lane-gather)
//  - u/z/B/C in bf16
// ---------------------------------------------------------------------------
template<int IMM>
__device__ __forceinline__ float swz(float x) {
  return __uint_as_float((unsigned)__builtin_amdgcn_ds_swizzle((int)__float_as_uint(x), IMM));
}

#define SLOAD(P, t0) { _Pragma("unroll") for (int j = 0; j < 4; ++j) { \
    P##_dt[j] = dp[(size_t)((t0)+j)*DI]; \
    P##_u[j]  = (float)ubp[(size_t)((t0)+j)*DI]; \
    P##_B[j]  = (float)bp[(size_t)((t0)+j)*XS]; \
    P##_C[j]  = (float)cp[(size_t)((t0)+j)*XS]; } }

#define SSTEP(P, j, t) { \
    const float dA = __expf(P##_dt[j] * Aval); \
    h = fmaf(h, dA, P##_dt[j] * P##_u[j] * P##_B[j]); \
    float v = h * P##_C[j]; \
    v += swz<0x041F>(v); v += swz<0x081F>(v); v += swz<0x101F>(v); \
    v += swz<0x201F>(v); v += swz<0x401F>(v); \
    v += __shfl_xor(v, 32, 64); \
    ystash = (((t) & 63) == lane) ? v : ystash; }

#define SCOMP(P, t0) { _Pragma("unroll") for (int j = 0; j < 4; ++j) SSTEP(P, j, (t0)+j) }

__global__ __launch_bounds__(256, 8) void scan_kernel(
    const float* __restrict__ delta, const __hip_bfloat16* __restrict__ ubf,
    const __hip_bfloat16* __restrict__ zbf, const __hip_bfloat16* __restrict__ xdbc,
    const float* __restrict__ A_log, const float* __restrict__ D_ssm,
    __hip_bfloat16* __restrict__ y)
{
  const int w = (int)((blockIdx.x * blockDim.x + threadIdx.x) >> 6);
  const int lane = threadIdx.x & 63;
  const int b = w >> 10;
  const int di = w & (DI - 1);
  const float Aval = -__expf(A_log[di * SS + lane]);
  const float Dd = D_ssm[di];
  const size_t rb = (size_t)b * LL;
  const float* __restrict__ dp = delta + rb * DI + di;
  const __hip_bfloat16* __restrict__ ubp = ubf + rb * DI + di;
  const __hip_bfloat16* __restrict__ zbp = zbf + rb * DI + di;
  const __hip_bfloat16* __restrict__ bp = xdbc + rb * XS + RR + lane;
  const __hip_bfloat16* __restrict__ cp = bp + SS;
  __hip_bfloat16* __restrict__ yp = y + rb * DI + di;

  float h = 0.f, ystash = 0.f;
  float a_dt[4], a_u[4], a_B[4], a_C[4];
  float b_dt[4], b_u[4], b_B[4], b_C[4];

  SLOAD(a, 0)
  for (int t0 = 0; t0 < LL; t0 += 8) {
    SLOAD(b, t0 + 4)
    SCOMP(a, t0)
    if (t0 + 8 < LL) SLOAD(a, t0 + 8)
    SCOMP(b, t0 + 4)
    if (((t0 + 8) & 63) == 0) {          // end of 64-step frame
      const int f0 = t0 - 56;
      const float uv = (float)ubp[(size_t)(f0 + lane) * DI];
      const float zv = (float)zbp[(size_t)(f0 + lane) * DI];
      const float yv = (ystash + uv * Dd) * (zv / (1.f + __expf(-zv)));
      yp[(size_t)(f0 + lane) * DI] = __float2bfloat16(yv);
      ystash = 0.f;
    }
  }
}

// ---------------------------------------------------------------------------
// Flash-style attention, fp32 compute, bf16 output.
// ---------------------------------------------------------------------------
__global__ __launch_bounds__(256) void attn_kernel(
    const float* __restrict__ q, const float* __restrict__ k,
    const float* __restrict__ v, __hip_bfloat16* __restrict__ o)
{
  __shared__ __align__(16) float Qs[64][68];
  __shared__ __align__(16) float KPs[64][68];
  __shared__ __align__(16) float Vs[64][68];
  const int tid = threadIdx.x;
  const int tx = tid & 15, ty = tid >> 4;
  const int bh = blockIdx.y;
  const int b = bh >> 3, hh = bh & 7;
  const int q0 = blockIdx.x << 6;
  const size_t base = (size_t)b * LL * DD + (size_t)hh * EE;

  for (int idx = tid; idx < 64 * 64; idx += 256) {
    const int qi = idx >> 6, e = idx & 63;
    Qs[qi][e] = q[base + (size_t)(q0 + qi) * DD + e] * 0.125f;
  }
  float m_i[4], l_i[4], acc[4][4];
#pragma unroll
  for (int i = 0; i < 4; ++i) {
    m_i[i] = -INFINITY; l_i[i] = 0.f;
#pragma unroll
    for (int j = 0; j < 4; ++j) acc[i][j] = 0.f;
  }

  for (int kt = 0; kt < LL / 64; ++kt) {
    __syncthreads();
    const int k0 = kt << 6;
    for (int idx = tid; idx < 64 * 64; idx += 256) {
      const int ki = idx >> 6, e = idx & 63;
      KPs[ki][e] = k[base + (size_t)(k0 + ki) * DD + e];
      Vs[ki][e]  = v[base + (size_t)(k0 + ki) * DD + e];
    }
    __syncthreads();

    float s[4][4] = {};
#pragma unroll 4
    for (int e4 = 0; e4 < 16; ++e4) {
      float qf[4][4], kf[4][4];
#pragma unroll
      for (int i = 0; i < 4; ++i) {
        const float4 a4 = *(const float4*)&Qs[(ty << 2) + i][e4 << 2];
        qf[i][0] = a4.x; qf[i][1] = a4.y; qf[i][2] = a4.z; qf[i][3] = a4.w;
      }
#pragma unroll
      for (int j = 0; j < 4; ++j) {
        const float4 b4 = *(const float4*)&KPs[(tx << 2) + j][e4 << 2];
        kf[j][0] = b4.x; kf[j][1] = b4.y; kf[j][2] = b4.z; kf[j][3] = b4.w;
      }
#pragma unroll
      for (int i = 0; i < 4; ++i)
#pragma unroll
        for (int j = 0; j < 4; ++j)
#pragma unroll
          for (int c = 0; c < 4; ++c)
            s[i][j] = fmaf(qf[i][c], kf[j][c], s[i][j]);
    }

    float p[4][4], alpha[4];
#pragma unroll
    for (int i = 0; i < 4; ++i) {
      float mt = fmaxf(fmaxf(s[i][0], s[i][1]), fmaxf(s[i][2], s[i][3]));
#pragma unroll
      for (int off = 1; off < 16; off <<= 1) mt = fmaxf(mt, __shfl_xor(mt, off, 16));
      const float mn = fmaxf(m_i[i], mt);
      alpha[i] = __expf(m_i[i] - mn);
      m_i[i] = mn;
      float rs = 0.f;
#pragma unroll
      for (int j = 0; j < 4; ++j) { p[i][j] = __expf(s[i][j] - mn); rs += p[i][j]; }
#pragma unroll
      for (int off = 1; off < 16; off <<= 1) rs += __shfl_xor(rs, off, 16);
      l_i[i] = l_i[i] * alpha[i] + rs;
    }

    __syncthreads();
#pragma unroll
    for (int i = 0; i < 4; ++i)
#pragma unroll
      for (int j = 0; j < 4; ++j)
        KPs[(ty << 2) + i][(tx << 2) + j] = p[i][j];
    __syncthreads();

#pragma unroll
    for (int i = 0; i < 4; ++i)
#pragma unroll
      for (int j = 0; j < 4; ++j) acc[i][j] *= alpha[i];

#pragma unroll 4
    for (int k4 = 0; k4 < 16; ++k4) {
      float vvf[4][4];
#pragma unroll
      for (int kk = 0; kk < 4; ++kk) {
        const float4 t4 = *(const float4*)&Vs[(k4 << 2) + kk][tx << 2];
        vvf[kk][0] = t4.x; vvf[kk][1] = t4.y; vvf[kk][2] = t4.z; vvf[kk][3] = t4.w;
      }
#pragma unroll
      for (int i = 0; i < 4; ++i) {
        const float4 p4 = *(const float4*)&KPs[(ty << 2) + i][k4 << 2];
        const float pf[4] = {p4.x, p4.y, p4.z, p4.w};
#pragma unroll
        for (int kk = 0; kk < 4; ++kk)
#pragma unroll
          for (int j = 0; j < 4; ++j)
            acc[i][j] = fmaf(pf[kk], vvf[kk][j], acc[i][j]);
      }
    }
  }

#pragma unroll
  for (int i = 0; i < 4; ++i) {
    const float inv = 1.f / l_i[i];
#pragma unroll
    for (int j = 0; j < 4; ++j)
      o[base + (size_t)(q0 + (ty << 2) + i) * DD + (tx << 2) + j] =
          __float2bfloat16(acc[i][j] * inv);
  }
}

// ---------------------------------------------------------------------------
// h = LN1(xf + attn + mamba); hn(bf16) = LN2(h).
// ---------------------------------------------------------------------------
__device__ __forceinline__ float block_sum512(float val, float* sm)
{
#pragma unroll
  for (int off = 32; off; off >>= 1) val += __shfl_xor(val, off, 64);
  const int wid = threadIdx.x >> 6;
  __syncthreads();
  if ((threadIdx.x & 63) == 0) sm[wid] = val;
  __syncthreads();
  return sm[0] + sm[1] + sm[2] + sm[3];
}

__global__ __launch_bounds__(256) void ln_fused(
    const float* __restrict__ xf, const float* __restrict__ ao,
    const float* __restrict__ mo,
    const float* __restrict__ g1, const float* __restrict__ b1,
    const float* __restrict__ g2, const float* __restrict__ b2,
    float* __restrict__ hout, __hip_bfloat16* __restrict__ hnout)
{
  __shared__ float sm[4];
  const size_t base = (size_t)blockIdx.x * DD;
  const int t = threadIdx.x;
  const float v0 = xf[base + t] + ao[base + t] + mo[base + t];
  const float v1 = xf[base + 256 + t] + ao[base + 256 + t] + mo[base + 256 + t];
  const float mean = block_sum512(v0 + v1, sm) * (1.f / DD);
  const float d0 = v0 - mean, d1 = v1 - mean;
  const float var = block_sum512(d0 * d0 + d1 * d1, sm) * (1.f / DD);
  const float rstd = rsqrtf(var + 1e-5f);
  const float h0 = d0 * rstd * g1[t] + b1[t];
  const float h1 = d1 * rstd * g1[t + 256] + b1[t + 256];
  hout[base + t] = h0;
  hout[base + 256 + t] = h1;
  const float mean2 = block_sum512(h0 + h1, sm) * (1.f / DD);
  const float e0 = h0 - mean2, e1 = h1 - mean2;
  const float var2 = block_sum512(e0 * e0 + e1 * e1, sm) * (1.f / DD);
  const float rstd2 = rsqrtf(var2 + 1e-6f);
  hnout[base + t] = __float2bfloat16(e0 * rstd2 * g2[t] + b2[t]);
  hnout[base + 256 + t] = __float2bfloat16(e1 * rstd2 * g2[t + 256] + b2[t + 256]);
}

// ---------------------------------------------------------------------------
extern "C" void kernel_launch(void* const* d_in, const int* in_sizes, int n_in,
                              void* d_out, int out_size, void* d_ws, size_t ws_size,
                              hipStream_t stream)
{
  const float* x         = (const float*)d_in[0];
  const float* Wq        = (const float*)d_in[2];
  const float* bq        = (const float*)d_in[3];
  const float* Wk        = (const float*)d_in[4];
  const float* bk        = (const float*)d_in[5];
  const float* Wv        = (const float*)d_in[6];
  const float* bv        = (const float*)d_in[7];
  const float* Wo        = (const float*)d_in[8];
  const float* bo        = (const float*)d_in[9];
  const float* in_proj_w = (const float*)d_in[10];
  const float* conv_w    = (const float*)d_in[11];
  const float* conv_b    = (const float*)d_in[12];
  const float* x_proj_w  = (const float*)d_in[13];
  const float* dt_proj_w = (const float*)d_in[14];
  const float* dt_proj_b = (const float*)d_in[15];
  const float* A_log     = (const float*)d_in[16];
  const float* D_ssm     = (const float*)d_in[17];
  const float* out_proj_w= (const float*)d_in[18];
  const float* ln1_g     = (const float*)d_in[19];
  const float* ln1_b     = (const float*)d_in[20];
  const float* ffn_w1    = (const float*)d_in[21];
  const float* ffn_b1    = (const float*)d_in[22];
  const float* ffn_w2    = (const float*)d_in[23];
  const float* ffn_b2    = (const float*)d_in[24];
  const float* ln2_g     = (const float*)d_in[25];
  const float* ln2_b     = (const float*)d_in[26];
  float* out = (float*)d_out;

  // ---- workspace regions (f32-element offsets), peak ~136 MB
  float* ws = (float*)d_ws;
  const size_t SZ = 4718592;                       // ML*512 f32 / ML*1024 bf16
  float* R1 = ws;                                  // upre_bf | q f32 | hbuf
  float* R2 = ws + SZ;                             // z_bf | k f32 | ffbf lo
  float* R3 = ws + 2 * SZ;                         // ubf  | v f32 | ffbf hi
  float* R4 = ws + 3 * SZ;                         // xdbc bf16 (737280 f32-eq)
  float* R5 = R4 + 737280;                         // delta f32 | mambab+aobuf
  float* R6 = R5 + 2 * SZ;                         // ybf | attnbf
  float* R7 = R6 + SZ;                             // xbf | hnbf (SZ/2)
  float* R8 = R7 + SZ / 2;                         // weights bf16

  __hip_bfloat16* upre_bf = (__hip_bfloat16*)R1;
  __hip_bfloat16* z_bf    = (__hip_bfloat16*)R2;
  __hip_bfloat16* ubf     = (__hip_bfloat16*)R3;
  __hip_bfloat16* xdbc_bf = (__hip_bfloat16*)R4;
  float*          deltab  = R5;
  float*          mambab  = R5;                    // after scan
  float*          aobuf   = R5 + SZ;
  __hip_bfloat16* ybf     = (__hip_bfloat16*)R6;
  __hip_bfloat16* attnbf  = (__hip_bfloat16*)R6;   // after out_proj
  __hip_bfloat16* xbf     = (__hip_bfloat16*)R7;
  __hip_bfloat16* hnbf    = (__hip_bfloat16*)R7;   // after qkv
  float*          qbuf    = R1;                    // after conv
  float*          kbuf    = R2;                    // after scan
  float*          vbuf    = R3;                    // after scan
  float*          hbuf    = R1;                    // after attn
  __hip_bfloat16* ffbf    = (__hip_bfloat16*)R2;   // spans R2+R3, after attn
  __hip_bfloat16* wbf     = (__hip_bfloat16*)R8;

  // weight offsets (bf16 elements) in wbf
  const size_t w_inproj = 0;              // 1048576
  const size_t w_xproj  = 1048576;        // 262144 (rows padded 160->256)
  const size_t w_dt     = 1310720;        // 32768
  const size_t w_out    = 1343488;        // 524288
  const size_t w_q      = 1867776;        // 262144
  const size_t w_k      = 2129920;
  const size_t w_v      = 2392064;
  const size_t w_o      = 2654208;
  const size_t w_f1     = 2916352;        // 1048576
  const size_t w_f2     = 3964928;        // 1048576

  const dim3 thr(256);
#define CVT(src, dst, n) cvt_bf16<<<dim3(((n)/4 + 255)/256), thr, 0, stream>>>(src, dst, n)
#define GEMM(Abf, lda_, Woff, Bptr, Rptr, Cptr, N_, K_, act_, ob_) \
  gemm_mfma<<<dim3((N_ + 127)/128, ML/128), thr, 0, stream>>>( \
      Abf, lda_, wbf + (Woff), Bptr, Rptr, (void*)(Cptr), ML, N_, K_, act_, ob_)

  // ---- weight + x conversion
  hipMemsetAsync((void*)(wbf + w_xproj + (size_t)160 * 1024), 0, (size_t)96 * 1024 * 2, stream);
  CVT(in_proj_w, wbf + w_inproj, 1048576);
  CVT(x_proj_w,  wbf + w_xproj,  163840);
  CVT(dt_proj_w, wbf + w_dt,     32768);
  CVT(out_proj_w,wbf + w_out,    524288);
  CVT(Wq,        wbf + w_q,      262144);
  CVT(Wk,        wbf + w_k,      262144);
  CVT(Wv,        wbf + w_v,      262144);
  CVT(Wo,        wbf + w_o,      262144);
  CVT(ffn_w1,    wbf + w_f1,     1048576);
  CVT(ffn_w2,    wbf + w_f2,     1048576);
  CVT(x,         xbf,            ML * DD);

  // ---- mamba branch
  GEMM(xbf, DD, w_inproj,                nullptr, nullptr, upre_bf, DI, DD, 0, 1);
  GEMM(xbf, DD, w_inproj + 524288,       nullptr, nullptr, z_bf,    DI, DD, 0, 1);
  conv_silu<<<dim3((ML * DI) / 256), thr, 0, stream>>>(upre_bf, conv_w, conv_b, ubf);
  GEMM(ubf, DI, w_xproj,                 nullptr, nullptr, xdbc_bf, XS, DI, 0, 1);
  GEMM(xdbc_bf, XS, w_dt,                dt_proj_b, nullptr, deltab, DI, RR, 2, 0);
  scan_kernel<<<dim3((BB * DI) / 4), thr, 0, stream>>>(
      deltab, ubf, z_bf, xdbc_bf, A_log, D_ssm, ybf);
  GEMM(ybf, DI, w_out,                   nullptr, nullptr, mambab, DD, DI, 0, 0);

  // ---- attention branch
  GEMM(xbf, DD, w_q, bq, nullptr, qbuf, DD, DD, 0, 0);
  GEMM(xbf, DD, w_k, bk, nullptr, kbuf, DD, DD, 0, 0);
  GEMM(xbf, DD, w_v, bv, nullptr, vbuf, DD, DD, 0, 0);
  attn_kernel<<<dim3(LL / 64, BB * HH), thr, 0, stream>>>(qbuf, kbuf, vbuf, attnbf);
  GEMM(attnbf, DD, w_o, bo, nullptr, aobuf, DD, DD, 0, 0);

  // ---- combine + LN1 + LN2
  ln_fused<<<dim3(ML), thr, 0, stream>>>(x, aobuf, mambab, ln1_g, ln1_b,
                                         ln2_g, ln2_b, hbuf, hnbf);

  // ---- FFN
  GEMM(hnbf, DD, w_f1, ffn_b1, nullptr, ffbf, DFF, DD, 1, 1);
  GEMM(ffbf, DFF, w_f2, ffn_b2, hbuf, out, DD, DFF, 0, 0);
#undef GEMM
#undef CVT
}

// Round 5
// 1111.043 us; speedup vs baseline: 3.0916x; 1.4638x over previous
//
#include <hip/hip_runtime.h>
#include <hip/hip_bf16.h>
#include <math.h>

#define BB 8
#define DD 512
#define HH 8
#define EE 64
#define DI 1024
#define SS 64
#define RR 32
#define KCONV 4
#define DFF 2048
#define LL 1152
#define ML (BB*LL)        // 9216
#define XS (RR + 2*SS)    // 160

typedef short bf16x8 __attribute__((ext_vector_type(8)));
typedef float f32x4 __attribute__((ext_vector_type(4)));
typedef unsigned short u16x4 __attribute__((ext_vector_type(4)));

#define GLD_LDS(g, l) \
  __builtin_amdgcn_global_load_lds((const __attribute__((address_space(1))) void*)(g), \
                                   (__attribute__((address_space(3))) void*)(l), 16, 0, 0)

__device__ __forceinline__ float bf2f(unsigned short u) {
  return __uint_as_float(((unsigned)u) << 16);
}

template<int IMM>
__device__ __forceinline__ float swz(float x) {
  return __uint_as_float((unsigned)__builtin_amdgcn_ds_swizzle((int)__float_as_uint(x), IMM));
}

// ---------------------------------------------------------------------------
// f32 -> bf16 conversion
// ---------------------------------------------------------------------------
__global__ __launch_bounds__(256) void cvt_bf16(
    const float* __restrict__ s, __hip_bfloat16* __restrict__ d, int n)
{
  const int i = (blockIdx.x * 256 + threadIdx.x) * 4;
  if (i + 3 < n) {
    const float4 v = *(const float4*)(s + i);
    __hip_bfloat16 t[4] = {__float2bfloat16(v.x), __float2bfloat16(v.y),
                           __float2bfloat16(v.z), __float2bfloat16(v.w)};
    *(ushort4*)(d + i) = *(const ushort4*)t;
  } else {
    for (int k = i; k < n; ++k) d[k] = __float2bfloat16(s[k]);
  }
}

// ---------------------------------------------------------------------------
// MFMA GEMM: C[m,n] = act( sum_k A[m,k]*W[n,k] + bias[n] ) + res[m,n]
// mode: 0 = f32 out, 1 = bf16 out, 2 = bf16 out transposed-per-head V layout
//       ([B,H,64 e,L key], for attention's PV B-operand)
// ---------------------------------------------------------------------------
__global__ __launch_bounds__(256) void gemm_mfma(
    const __hip_bfloat16* __restrict__ A, int lda,
    const __hip_bfloat16* __restrict__ W,
    const float* __restrict__ bias,
    const float* __restrict__ res,
    void* __restrict__ Cv,
    int M, int N, int K, int act, int mode)
{
  __shared__ __align__(16) __hip_bfloat16 As[128 * 32];
  __shared__ __align__(16) __hip_bfloat16 Ws[128 * 32];
  const int tid = threadIdx.x;
  const int wid = tid >> 6, lane = tid & 63;
  const int wr = wid >> 1, wc = wid & 1;
  const int m0 = blockIdx.y << 7, n0 = blockIdx.x << 7;
  const int r1 = tid >> 2;
  const int c1 = (tid & 3) << 3;

  const __hip_bfloat16* ga0 = A + (size_t)(m0 + r1) * lda + c1;
  const __hip_bfloat16* ga1 = A + (size_t)(m0 + 64 + r1) * lda + c1;
  const __hip_bfloat16* gw0 = W + (size_t)(n0 + r1) * K + c1;
  const __hip_bfloat16* gw1 = W + (size_t)(n0 + 64 + r1) * K + c1;
  char* lA0 = (char*)As + wid * 1024;
  char* lA1 = lA0 + 4096;
  char* lW0 = (char*)Ws + wid * 1024;
  char* lW1 = lW0 + 4096;

  f32x4 acc[4][4];
#pragma unroll
  for (int i = 0; i < 4; ++i)
#pragma unroll
    for (int j = 0; j < 4; ++j) acc[i][j] = (f32x4){0.f, 0.f, 0.f, 0.f};

  const int fm = lane & 15;
  const int q8 = (lane >> 4) << 3;

  for (int kt = 0; kt < K; kt += 32) {
    __syncthreads();
    GLD_LDS(ga0, lA0); GLD_LDS(ga1, lA1);
    GLD_LDS(gw0, lW0); GLD_LDS(gw1, lW1);
    ga0 += 32; ga1 += 32; gw0 += 32; gw1 += 32;
    __syncthreads();

    bf16x8 af[4], wf[4];
#pragma unroll
    for (int i = 0; i < 4; ++i)
      af[i] = *(const bf16x8*)((const short*)As + (wr * 64 + i * 16 + fm) * 32 + q8);
#pragma unroll
    for (int j = 0; j < 4; ++j)
      wf[j] = *(const bf16x8*)((const short*)Ws + (wc * 64 + j * 16 + fm) * 32 + q8);
#pragma unroll
    for (int i = 0; i < 4; ++i)
#pragma unroll
      for (int j = 0; j < 4; ++j)
        acc[i][j] = __builtin_amdgcn_mfma_f32_16x16x32_bf16(af[i], wf[j], acc[i][j], 0, 0, 0);
  }

  const int rquad = (lane >> 4) << 2;
#pragma unroll
  for (int j = 0; j < 4; ++j) {
    const int n = n0 + wc * 64 + j * 16 + fm;
    if (n < N) {
      const float bv = bias ? bias[n] : 0.f;
#pragma unroll
      for (int i = 0; i < 4; ++i) {
        const int mb = m0 + wr * 64 + i * 16 + rquad;
#pragma unroll
        for (int r = 0; r < 4; ++r) {
          const int m = mb + r;
          float v = acc[i][j][r] + bv;
          if (act == 1) v = 0.5f * v * (1.f + erff(v * 0.70710678118654752f));
          else if (act == 2) v = fmaxf(v, 0.f) + log1pf(expf(-fabsf(v)));
          if (mode == 2) {
            const int bb2 = m / LL;
            const int key = m - bb2 * LL;
            ((__hip_bfloat16*)Cv)[((size_t)(bb2 * HH + (n >> 6)) * EE + (n & 63)) * LL + key] =
                __float2bfloat16(v);
          } else {
            const size_t off = (size_t)m * N + n;
            if (res) v += res[off];
            if (mode == 1) ((__hip_bfloat16*)Cv)[off] = __float2bfloat16(v);
            else ((float*)Cv)[off] = v;
          }
        }
      }
    }
  }
}

// ---------------------------------------------------------------------------
// Causal depthwise conv1d (kernel 4) + SiLU, bf16 in/out.
// ---------------------------------------------------------------------------
__global__ __launch_bounds__(256) void conv_silu(
    const __hip_bfloat16* __restrict__ upre, const float* __restrict__ cw,
    const float* __restrict__ cb, __hip_bfloat16* __restrict__ uout)
{
  const size_t idx = (size_t)blockIdx.x * 256 + threadIdx.x;
  if (idx >= (size_t)ML * DI) return;
  const int di = (int)(idx & (DI - 1));
  const int t = (int)((idx >> 10) % LL);
  float acc = cb[di];
#pragma unroll
  for (int k = 0; k < KCONV; ++k) {
    if (t - (KCONV - 1) + k >= 0)
      acc = fmaf((float)upre[idx - (size_t)(KCONV - 1 - k) * DI], cw[di * KCONV + k], acc);
  }
  uout[idx] = __float2bfloat16(acc / (1.f + __expf(-acc)));
}

// ---------------------------------------------------------------------------
// Selective-scan v4: 4 states/lane, 16 lanes/channel, 4 channels/wave.
// 2048 waves total. Reduction = 4 xor-swizzles within 16-lane groups.
// Gate/D-term applied in per-16-step frame epilogue via lane-gather.
// ---------------------------------------------------------------------------
#define SLOAD(P, t0) { _Pragma("unroll") for (int j = 0; j < 4; ++j) { \
    P##_dt[j] = dp[(size_t)((t0)+j)*DI]; \
    P##_u[j]  = bf2f(ubp[(size_t)((t0)+j)*DI]); \
    P##_B[j]  = *(const u16x4*)(Bp + (size_t)((t0)+j)*XS); \
    P##_C[j]  = *(const u16x4*)(Cp + (size_t)((t0)+j)*XS); } }

#define SSTEP(P, j, t) { \
    const float dtu = P##_dt[j] * P##_u[j]; \
    h0 = fmaf(h0, __expf(P##_dt[j] * Av[0]), dtu * bf2f(P##_B[j][0])); \
    h1 = fmaf(h1, __expf(P##_dt[j] * Av[1]), dtu * bf2f(P##_B[j][1])); \
    h2 = fmaf(h2, __expf(P##_dt[j] * Av[2]), dtu * bf2f(P##_B[j][2])); \
    h3 = fmaf(h3, __expf(P##_dt[j] * Av[3]), dtu * bf2f(P##_B[j][3])); \
    float part = h0 * bf2f(P##_C[j][0]); \
    part = fmaf(h1, bf2f(P##_C[j][1]), part); \
    part = fmaf(h2, bf2f(P##_C[j][2]), part); \
    part = fmaf(h3, bf2f(P##_C[j][3]), part); \
    part += swz<0x041F>(part); part += swz<0x081F>(part); \
    part += swz<0x101F>(part); part += swz<0x201F>(part); \
    ystash = (((t) & 15) == s4) ? part : ystash; }

#define SCOMP(P, t0) { _Pragma("unroll") for (int j = 0; j < 4; ++j) SSTEP(P, j, (t0)+j) }

__global__ __launch_bounds__(256) void scan_kernel(
    const float* __restrict__ delta, const __hip_bfloat16* __restrict__ ubf,
    const __hip_bfloat16* __restrict__ zbf, const __hip_bfloat16* __restrict__ xdbc,
    const float* __restrict__ A_log, const float* __restrict__ D_ssm,
    __hip_bfloat16* __restrict__ y)
{
  const int wv = (int)((blockIdx.x * 256 + threadIdx.x) >> 6);   // 0..2047
  const int lane = threadIdx.x & 63;
  const int c = lane >> 4;
  const int s4 = lane & 15;
  const int g = (wv << 2) + c;        // global channel
  const int b = g >> 10;
  const int di = g & (DI - 1);
  float Av[4];
#pragma unroll
  for (int kk = 0; kk < 4; ++kk)
    Av[kk] = -__expf(A_log[di * SS + (s4 << 2) + kk]);
  const float Dd = D_ssm[di];
  const size_t rb = (size_t)b * LL;
  const float* __restrict__ dp = delta + rb * DI + di;
  const unsigned short* __restrict__ ubp = (const unsigned short*)ubf + rb * DI + di;
  const unsigned short* __restrict__ zbp = (const unsigned short*)zbf + rb * DI + di;
  const unsigned short* __restrict__ Bp = (const unsigned short*)xdbc + rb * XS + RR + (s4 << 2);
  const unsigned short* __restrict__ Cp = Bp + SS;
  __hip_bfloat16* __restrict__ yp = y + rb * DI + di;

  float h0 = 0.f, h1 = 0.f, h2 = 0.f, h3 = 0.f;
  float ystash = 0.f;
  float a_dt[4], a_u[4]; u16x4 a_B[4], a_C[4];
  float b_dt[4], b_u[4]; u16x4 b_B[4], b_C[4];

  SLOAD(a, 0)
  for (int t0 = 0; t0 < LL; t0 += 8) {
    SLOAD(b, t0 + 4)
    SCOMP(a, t0)
    if (t0 + 8 < LL) SLOAD(a, t0 + 8)
    SCOMP(b, t0 + 4)
    if (((t0 + 8) & 15) == 0) {        // end of 16-step frame
      const int tf = t0 - 8 + s4;
      const float uv = bf2f(ubp[(size_t)tf * DI]);
      const float zv = bf2f(zbp[(size_t)tf * DI]);
      const float yv = (ystash + uv * Dd) * (zv / (1.f + __expf(-zv)));
      yp[(size_t)tf * DI] = __float2bfloat16(yv);
      ystash = 0.f;
    }
  }
}

// ---------------------------------------------------------------------------
// MFMA flash attention. Block = 64 queries x one (b,h); 4 waves x 16 queries.
// Q,K: bf16 [B,L,D] head-sliced. Vt: bf16 [B*H, 64 e, L keys]. Out bf16 [B,L,D].
// NOTE: each staging thread writes TWO uint4 (16 bf16 = 32 B) per row chunk.
// ---------------------------------------------------------------------------
__global__ __launch_bounds__(256) void attn_mfma(
    const __hip_bfloat16* __restrict__ qg, const __hip_bfloat16* __restrict__ kg,
    const __hip_bfloat16* __restrict__ vtg, __hip_bfloat16* __restrict__ og)
{
  __shared__ __align__(16) __hip_bfloat16 Qs[64][72];
  __shared__ __align__(16) __hip_bfloat16 Ks[64][72];
  __shared__ __align__(16) __hip_bfloat16 Vts[64][72];
  __shared__ __align__(16) __hip_bfloat16 Ps[4][16][72];
  const int tid = threadIdx.x;
  const int w = tid >> 6, lane = tid & 63;
  const int bh = blockIdx.y;
  const int b = bh >> 3, hh = bh & 7;
  const int q0 = blockIdx.x << 6;
  const size_t qkbase = (size_t)b * LL * DD + (size_t)hh * EE;
  const size_t vtbase = (size_t)bh * EE * LL;

  const int srow = tid >> 2, sch = (tid & 3) << 4;   // 16 elements per chunk
  {
    const __hip_bfloat16* src = qg + qkbase + (size_t)(q0 + srow) * DD + sch;
    *(uint4*)&Qs[srow][sch]     = *(const uint4*)src;
    *(uint4*)&Qs[srow][sch + 8] = *(const uint4*)(src + 8);
  }
  __syncthreads();

  const int fm = lane & 15;
  const int q8 = (lane >> 4) << 3;
  bf16x8 af0 = *(const bf16x8*)&Qs[w * 16 + fm][q8];
  bf16x8 af1 = *(const bf16x8*)&Qs[w * 16 + fm][32 + q8];

  f32x4 oacc[4];
  float m_i[4], l_i[4];
#pragma unroll
  for (int r = 0; r < 4; ++r) { m_i[r] = -INFINITY; l_i[r] = 0.f; }
#pragma unroll
  for (int j = 0; j < 4; ++j) oacc[j] = (f32x4){0.f, 0.f, 0.f, 0.f};

  for (int kt = 0; kt < LL / 64; ++kt) {
    const int k0 = kt << 6;
    __syncthreads();
    {
      const __hip_bfloat16* ksrc = kg + qkbase + (size_t)(k0 + srow) * DD + sch;
      const __hip_bfloat16* vsrc = vtg + vtbase + (size_t)srow * LL + k0 + sch;
      *(uint4*)&Ks[srow][sch]      = *(const uint4*)ksrc;
      *(uint4*)&Ks[srow][sch + 8]  = *(const uint4*)(ksrc + 8);
      *(uint4*)&Vts[srow][sch]     = *(const uint4*)vsrc;
      *(uint4*)&Vts[srow][sch + 8] = *(const uint4*)(vsrc + 8);
    }
    __syncthreads();

    f32x4 sacc[4];
#pragma unroll
    for (int j = 0; j < 4; ++j) sacc[j] = (f32x4){0.f, 0.f, 0.f, 0.f};
#pragma unroll
    for (int j = 0; j < 4; ++j) {
      bf16x8 kf0 = *(const bf16x8*)&Ks[j * 16 + fm][q8];
      bf16x8 kf1 = *(const bf16x8*)&Ks[j * 16 + fm][32 + q8];
      sacc[j] = __builtin_amdgcn_mfma_f32_16x16x32_bf16(af0, kf0, sacc[j], 0, 0, 0);
      sacc[j] = __builtin_amdgcn_mfma_f32_16x16x32_bf16(af1, kf1, sacc[j], 0, 0, 0);
    }

    float alpha[4];
#pragma unroll
    for (int r = 0; r < 4; ++r) {
#pragma unroll
      for (int j = 0; j < 4; ++j) sacc[j][r] *= 0.125f;
      float mt = fmaxf(fmaxf(sacc[0][r], sacc[1][r]), fmaxf(sacc[2][r], sacc[3][r]));
      mt = fmaxf(mt, swz<0x041F>(mt)); mt = fmaxf(mt, swz<0x081F>(mt));
      mt = fmaxf(mt, swz<0x101F>(mt)); mt = fmaxf(mt, swz<0x201F>(mt));
      const float mn = fmaxf(m_i[r], mt);
      alpha[r] = __expf(m_i[r] - mn);
      m_i[r] = mn;
      float p[4], rs = 0.f;
#pragma unroll
      for (int j = 0; j < 4; ++j) { p[j] = __expf(sacc[j][r] - mn); rs += p[j]; }
      rs += swz<0x041F>(rs); rs += swz<0x081F>(rs);
      rs += swz<0x101F>(rs); rs += swz<0x201F>(rs);
      l_i[r] = l_i[r] * alpha[r] + rs;
      const int qrow = ((lane >> 4) << 2) + r;
#pragma unroll
      for (int j = 0; j < 4; ++j)
        Ps[w][qrow][j * 16 + fm] = __float2bfloat16(p[j]);
    }
#pragma unroll
    for (int j = 0; j < 4; ++j)
#pragma unroll
      for (int r = 0; r < 4; ++r) oacc[j][r] *= alpha[r];

    bf16x8 pf0 = *(const bf16x8*)&Ps[w][fm][q8];
    bf16x8 pf1 = *(const bf16x8*)&Ps[w][fm][32 + q8];
#pragma unroll
    for (int j = 0; j < 4; ++j) {
      bf16x8 v0 = *(const bf16x8*)&Vts[j * 16 + fm][q8];
      bf16x8 v1 = *(const bf16x8*)&Vts[j * 16 + fm][32 + q8];
      oacc[j] = __builtin_amdgcn_mfma_f32_16x16x32_bf16(pf0, v0, oacc[j], 0, 0, 0);
      oacc[j] = __builtin_amdgcn_mfma_f32_16x16x32_bf16(pf1, v1, oacc[j], 0, 0, 0);
    }
  }

#pragma unroll
  for (int r = 0; r < 4; ++r) {
    const float inv = 1.f / l_i[r];
    const int qq = q0 + w * 16 + ((lane >> 4) << 2) + r;
#pragma unroll
    for (int j = 0; j < 4; ++j)
      og[qkbase + (size_t)qq * DD + j * 16 + fm] = __float2bfloat16(oacc[j][r] * inv);
  }
}

// ---------------------------------------------------------------------------
// h = LN1(xf + attn + mamba); hn(bf16) = LN2(h).
// ---------------------------------------------------------------------------
__device__ __forceinline__ float block_sum512(float val, float* sm)
{
#pragma unroll
  for (int off = 32; off; off >>= 1) val += __shfl_xor(val, off, 64);
  const int wid = threadIdx.x >> 6;
  __syncthreads();
  if ((threadIdx.x & 63) == 0) sm[wid] = val;
  __syncthreads();
  return sm[0] + sm[1] + sm[2] + sm[3];
}

__global__ __launch_bounds__(256) void ln_fused(
    const float* __restrict__ xf, const float* __restrict__ ao,
    const float* __restrict__ mo,
    const float* __restrict__ g1, const float* __restrict__ b1,
    const float* __restrict__ g2, const float* __restrict__ b2,
    float* __restrict__ hout, __hip_bfloat16* __restrict__ hnout)
{
  __shared__ float sm[4];
  const size_t base = (size_t)blockIdx.x * DD;
  const int t = threadIdx.x;
  const float v0 = xf[base + t] + ao[base + t] + mo[base + t];
  const float v1 = xf[base + 256 + t] + ao[base + 256 + t] + mo[base + 256 + t];
  const float mean = block_sum512(v0 + v1, sm) * (1.f / DD);
  const float d0 = v0 - mean, d1 = v1 - mean;
  const float var = block_sum512(d0 * d0 + d1 * d1, sm) * (1.f / DD);
  const float rstd = rsqrtf(var + 1e-5f);
  const float h0 = d0 * rstd * g1[t] + b1[t];
  const float h1 = d1 * rstd * g1[t + 256] + b1[t + 256];
  hout[base + t] = h0;
  hout[base + 256 + t] = h1;
  const float mean2 = block_sum512(h0 + h1, sm) * (1.f / DD);
  const float e0 = h0 - mean2, e1 = h1 - mean2;
  const float var2 = block_sum512(e0 * e0 + e1 * e1, sm) * (1.f / DD);
  const float rstd2 = rsqrtf(var2 + 1e-6f);
  hnout[base + t] = __float2bfloat16(e0 * rstd2 * g2[t] + b2[t]);
  hnout[base + 256 + t] = __float2bfloat16(e1 * rstd2 * g2[t + 256] + b2[t + 256]);
}

// ---------------------------------------------------------------------------
extern "C" void kernel_launch(void* const* d_in, const int* in_sizes, int n_in,
                              void* d_out, int out_size, void* d_ws, size_t ws_size,
                              hipStream_t stream)
{
  const float* x         = (const float*)d_in[0];
  const float* Wq        = (const float*)d_in[2];
  const float* bq        = (const float*)d_in[3];
  const float* Wk        = (const float*)d_in[4];
  const float* bk        = (const float*)d_in[5];
  const float* Wv        = (const float*)d_in[6];
  const float* bv        = (const float*)d_in[7];
  const float* Wo        = (const float*)d_in[8];
  const float* bo        = (const float*)d_in[9];
  const float* in_proj_w = (const float*)d_in[10];
  const float* conv_w    = (const float*)d_in[11];
  const float* conv_b    = (const float*)d_in[12];
  const float* x_proj_w  = (const float*)d_in[13];
  const float* dt_proj_w = (const float*)d_in[14];
  const float* dt_proj_b = (const float*)d_in[15];
  const float* A_log     = (const float*)d_in[16];
  const float* D_ssm     = (const float*)d_in[17];
  const float* out_proj_w= (const float*)d_in[18];
  const float* ln1_g     = (const float*)d_in[19];
  const float* ln1_b     = (const float*)d_in[20];
  const float* ffn_w1    = (const float*)d_in[21];
  const float* ffn_b1    = (const float*)d_in[22];
  const float* ffn_w2    = (const float*)d_in[23];
  const float* ffn_b2    = (const float*)d_in[24];
  const float* ln2_g     = (const float*)d_in[25];
  const float* ln2_b     = (const float*)d_in[26];
  float* out = (float*)d_out;

  // ---- workspace layout (f32-unit offsets), peak ~136 MB
  float* ws = (float*)d_ws;
  const size_t OF_XBF = 2506752;      // xbf bf16 [ML*512]
  const size_t OF_UQ  = 4866048;      // upre_bf | q,k bf16
  const size_t OF_ZV  = 9584640;      // z_bf | vt bf16
  const size_t OF_UH  = 14303232;     // ubf | hbuf f32
  const size_t OF_XD  = 19021824;     // xdbc bf16
  const size_t OF_DF  = 19759104;     // delta f32 | mambab+aobuf | ffbf
  const size_t OF_YA  = 29196288;     // ybf | attnbf + hnbf

  __hip_bfloat16* wbf     = (__hip_bfloat16*)ws;
  __hip_bfloat16* xbf     = (__hip_bfloat16*)(ws + OF_XBF);
  __hip_bfloat16* upre_bf = (__hip_bfloat16*)(ws + OF_UQ);
  __hip_bfloat16* qbf     = upre_bf;
  __hip_bfloat16* kbf     = upre_bf + (size_t)ML * DD;
  __hip_bfloat16* z_bf    = (__hip_bfloat16*)(ws + OF_ZV);
  __hip_bfloat16* vtbf    = z_bf;
  __hip_bfloat16* ubf     = (__hip_bfloat16*)(ws + OF_UH);
  float*          hbuf    = ws + OF_UH;
  __hip_bfloat16* xdbc_bf = (__hip_bfloat16*)(ws + OF_XD);
  float*          deltab  = ws + OF_DF;
  float*          mambab  = deltab;
  float*          aobuf   = deltab + (size_t)ML * DD;
  __hip_bfloat16* ffbf    = (__hip_bfloat16*)(ws + OF_DF);
  __hip_bfloat16* ybf     = (__hip_bfloat16*)(ws + OF_YA);
  __hip_bfloat16* attnbf  = ybf;
  __hip_bfloat16* hnbf    = (__hip_bfloat16*)(ws + OF_YA + 2359296);

  // weight offsets (bf16 elements) in wbf
  const size_t w_inproj = 0;
  const size_t w_xproj  = 1048576;    // rows padded 160->256
  const size_t w_dt     = 1310720;
  const size_t w_out    = 1343488;
  const size_t w_q      = 1867776;
  const size_t w_k      = 2129920;
  const size_t w_v      = 2392064;
  const size_t w_o      = 2654208;
  const size_t w_f1     = 2916352;
  const size_t w_f2     = 3964928;

  const dim3 thr(256);
#define CVT(src, dst, n) cvt_bf16<<<dim3(((n)/4 + 255)/256), thr, 0, stream>>>(src, dst, n)
#define GEMM(Abf, lda_, Woff, Bptr, Rptr, Cptr, N_, K_, act_, md_) \
  gemm_mfma<<<dim3((N_ + 127)/128, ML/128), thr, 0, stream>>>( \
      Abf, lda_, wbf + (Woff), Bptr, Rptr, (void*)(Cptr), ML, N_, K_, act_, md_)

  hipMemsetAsync((void*)(wbf + w_xproj + (size_t)160 * 1024), 0, (size_t)96 * 1024 * 2, stream);
  CVT(in_proj_w, wbf + w_inproj, 1048576);
  CVT(x_proj_w,  wbf + w_xproj,  163840);
  CVT(dt_proj_w, wbf + w_dt,     32768);
  CVT(out_proj_w,wbf + w_out,    524288);
  CVT(Wq,        wbf + w_q,      262144);
  CVT(Wk,        wbf + w_k,      262144);
  CVT(Wv,        wbf + w_v,      262144);
  CVT(Wo,        wbf + w_o,      262144);
  CVT(ffn_w1,    wbf + w_f1,     1048576);
  CVT(ffn_w2,    wbf + w_f2,     1048576);
  CVT(x,         xbf,            ML * DD);

  // ---- mamba branch
  GEMM(xbf, DD, w_inproj,          nullptr, nullptr, upre_bf, DI, DD, 0, 1);
  GEMM(xbf, DD, w_inproj + 524288, nullptr, nullptr, z_bf,    DI, DD, 0, 1);
  conv_silu<<<dim3((ML * DI) / 256), thr, 0, stream>>>(upre_bf, conv_w, conv_b, ubf);
  GEMM(ubf, DI, w_xproj,           nullptr, nullptr, xdbc_bf, XS, DI, 0, 1);
  GEMM(xdbc_bf, XS, w_dt,          dt_proj_b, nullptr, deltab, DI, RR, 2, 0);
  scan_kernel<<<dim3(512), thr, 0, stream>>>(
      deltab, ubf, z_bf, xdbc_bf, A_log, D_ssm, ybf);
  GEMM(ybf, DI, w_out,             nullptr, nullptr, mambab, DD, DI, 0, 0);

  // ---- attention branch (after scan: q/k reuse upre region, vt reuses z)
  GEMM(xbf, DD, w_q, bq, nullptr, qbf,  DD, DD, 0, 1);
  GEMM(xbf, DD, w_k, bk, nullptr, kbf,  DD, DD, 0, 1);
  GEMM(xbf, DD, w_v, bv, nullptr, vtbf, DD, DD, 0, 2);
  attn_mfma<<<dim3(LL / 64, BB * HH), thr, 0, stream>>>(qbf, kbf, vtbf, attnbf);
  GEMM(attnbf, DD, w_o, bo, nullptr, aobuf, DD, DD, 0, 0);

  // ---- combine + LN1 + LN2
  ln_fused<<<dim3(ML), thr, 0, stream>>>(x, aobuf, mambab, ln1_g, ln1_b,
                                         ln2_g, ln2_b, hbuf, hnbf);

  // ---- FFN
  GEMM(hnbf, DD, w_f1, ffn_b1, nullptr, ffbf, DFF, DD, 1, 1);
  GEMM(ffbf, DFF, w_f2, ffn_b2, hbuf, out, DD, DFF, 0, 0);
#undef GEMM
#undef CVT
}

// Round 7
// 1042.495 us; speedup vs baseline: 3.2948x; 1.0658x over previous
//
#include <hip/hip_runtime.h>
#include <hip/hip_bf16.h>
#include <math.h>

#define BB 8
#define DD 512
#define HH 8
#define EE 64
#define DI 1024
#define SS 64
#define RR 32
#define KCONV 4
#define DFF 2048
#define LL 1152
#define ML (BB*LL)        // 9216
#define XS (RR + 2*SS)    // 160
#define ZSTR 2048

typedef short bf16x8 __attribute__((ext_vector_type(8)));
typedef float f32x4 __attribute__((ext_vector_type(4)));
typedef unsigned short u16x4 __attribute__((ext_vector_type(4)));

#define GLD_LDS(g, l) \
  __builtin_amdgcn_global_load_lds((const __attribute__((address_space(1))) void*)(g), \
                                   (__attribute__((address_space(3))) void*)(l), 16, 0, 0)

__device__ __forceinline__ float bf2f(unsigned short u) {
  return __uint_as_float(((unsigned)u) << 16);
}

template<int IMM>
__device__ __forceinline__ float swz(float x) {
  return __uint_as_float((unsigned)__builtin_amdgcn_ds_swizzle((int)__float_as_uint(x), IMM));
}

// ---------------------------------------------------------------------------
// f32 -> bf16 conversion
// ---------------------------------------------------------------------------
__global__ __launch_bounds__(256) void cvt_bf16(
    const float* __restrict__ s, __hip_bfloat16* __restrict__ d, int n)
{
  const int i = (blockIdx.x * 256 + threadIdx.x) * 4;
  if (i + 3 < n) {
    const float4 v = *(const float4*)(s + i);
    __hip_bfloat16 t[4] = {__float2bfloat16(v.x), __float2bfloat16(v.y),
                           __float2bfloat16(v.z), __float2bfloat16(v.w)};
    *(ushort4*)(d + i) = *(const ushort4*)t;
  } else {
    for (int k = i; k < n; ++k) d[k] = __float2bfloat16(s[k]);
  }
}

// ---------------------------------------------------------------------------
// MFMA GEMM: C[m,n] = act( sum_k A[m,k]*W[n,k] + bias[n] ) + res[m,n]
// mode: 0 = f32 out; 1 = bf16 out; 3 = qkv split: n<1024 -> Cv[m*1024+n]
//       (bf16), n>=1024 -> V^T-per-head scatter into Cv2 [B*H, 64e, L].
// ---------------------------------------------------------------------------
__global__ __launch_bounds__(256) void gemm_mfma(
    const __hip_bfloat16* __restrict__ A, int lda,
    const __hip_bfloat16* __restrict__ W,
    const float* __restrict__ bias,
    const float* __restrict__ res,
    void* __restrict__ Cv, void* __restrict__ Cv2,
    int M, int N, int K, int act, int mode)
{
  __shared__ __align__(16) __hip_bfloat16 As[128 * 32];
  __shared__ __align__(16) __hip_bfloat16 Ws[128 * 32];
  const int tid = threadIdx.x;
  const int wid = tid >> 6, lane = tid & 63;
  const int wr = wid >> 1, wc = wid & 1;
  const int m0 = blockIdx.y << 7, n0 = blockIdx.x << 7;
  const int r1 = tid >> 2;
  const int c1 = (tid & 3) << 3;

  const __hip_bfloat16* ga0 = A + (size_t)(m0 + r1) * lda + c1;
  const __hip_bfloat16* ga1 = A + (size_t)(m0 + 64 + r1) * lda + c1;
  const __hip_bfloat16* gw0 = W + (size_t)(n0 + r1) * K + c1;
  const __hip_bfloat16* gw1 = W + (size_t)(n0 + 64 + r1) * K + c1;
  char* lA0 = (char*)As + wid * 1024;
  char* lA1 = lA0 + 4096;
  char* lW0 = (char*)Ws + wid * 1024;
  char* lW1 = lW0 + 4096;

  f32x4 acc[4][4];
#pragma unroll
  for (int i = 0; i < 4; ++i)
#pragma unroll
    for (int j = 0; j < 4; ++j) acc[i][j] = (f32x4){0.f, 0.f, 0.f, 0.f};

  const int fm = lane & 15;
  const int q8 = (lane >> 4) << 3;

  for (int kt = 0; kt < K; kt += 32) {
    __syncthreads();
    GLD_LDS(ga0, lA0); GLD_LDS(ga1, lA1);
    GLD_LDS(gw0, lW0); GLD_LDS(gw1, lW1);
    ga0 += 32; ga1 += 32; gw0 += 32; gw1 += 32;
    __syncthreads();

    bf16x8 af[4], wf[4];
#pragma unroll
    for (int i = 0; i < 4; ++i)
      af[i] = *(const bf16x8*)((const short*)As + (wr * 64 + i * 16 + fm) * 32 + q8);
#pragma unroll
    for (int j = 0; j < 4; ++j)
      wf[j] = *(const bf16x8*)((const short*)Ws + (wc * 64 + j * 16 + fm) * 32 + q8);
#pragma unroll
    for (int i = 0; i < 4; ++i)
#pragma unroll
      for (int j = 0; j < 4; ++j)
        acc[i][j] = __builtin_amdgcn_mfma_f32_16x16x32_bf16(af[i], wf[j], acc[i][j], 0, 0, 0);
  }

  const int rquad = (lane >> 4) << 2;
#pragma unroll
  for (int j = 0; j < 4; ++j) {
    const int n = n0 + wc * 64 + j * 16 + fm;
    if (n < N) {
      const float bv = bias ? bias[n] : 0.f;
#pragma unroll
      for (int i = 0; i < 4; ++i) {
        const int mb = m0 + wr * 64 + i * 16 + rquad;
#pragma unroll
        for (int r = 0; r < 4; ++r) {
          const int m = mb + r;
          float v = acc[i][j][r] + bv;
          if (act == 1) v = 0.5f * v * (1.f + erff(v * 0.70710678118654752f));
          else if (act == 2) v = fmaxf(v, 0.f) + log1pf(expf(-fabsf(v)));
          if (mode == 3) {
            if (n < 1024) {
              ((__hip_bfloat16*)Cv)[(size_t)m * 1024 + n] = __float2bfloat16(v);
            } else {
              const int e = n - 1024;
              const int bb2 = m / LL;
              const int key = m - bb2 * LL;
              ((__hip_bfloat16*)Cv2)[((size_t)(bb2 * HH + (e >> 6)) * EE + (e & 63)) * LL + key] =
                  __float2bfloat16(v);
            }
          } else {
            const size_t off = (size_t)m * N + n;
            if (res) v += res[off];
            if (mode == 1) ((__hip_bfloat16*)Cv)[off] = __float2bfloat16(v);
            else ((float*)Cv)[off] = v;
          }
        }
      }
    }
  }
}

// ---------------------------------------------------------------------------
// Causal depthwise conv1d (kernel 4) + SiLU.
// Input: interleaved in_proj output xz [ML, 2048] (u = cols 0..1023).
// Output: dense ubf [ML, 1024].
// ---------------------------------------------------------------------------
__global__ __launch_bounds__(256) void conv_silu(
    const __hip_bfloat16* __restrict__ xz, const float* __restrict__ cw,
    const float* __restrict__ cb, __hip_bfloat16* __restrict__ uout)
{
  const size_t idx = (size_t)blockIdx.x * 256 + threadIdx.x;
  if (idx >= (size_t)ML * DI) return;
  const int di = (int)(idx & (DI - 1));
  const int row = (int)(idx >> 10);
  const int t = row % LL;
  float acc = cb[di];
#pragma unroll
  for (int k = 0; k < KCONV; ++k) {
    if (t - (KCONV - 1) + k >= 0)
      acc = fmaf((float)xz[(size_t)(row - (KCONV - 1 - k)) * ZSTR + di],
                 cw[di * KCONV + k], acc);
  }
  uout[idx] = __float2bfloat16(acc / (1.f + __expf(-acc)));
}

// ---------------------------------------------------------------------------
// Selective-scan v5: 4 states/lane, 16 lanes/channel, 4 channels/wave.
//  - inner step loop: NO cross-lane ops; stash partial dot in Pp[step&15]
//  - per-16-step frame: butterfly reduce-scatter (xor 1/2/4/8) -> lane s4
//    holds step t0+s4's total
//  - 4-tile ring prefetch (12-step lookahead) + frame-ahead u/z prefetch
// ---------------------------------------------------------------------------
#define SLOAD(P_, t0_) { _Pragma("unroll") for (int j = 0; j < 4; ++j) { \
    P_##_dt[j] = dp[(size_t)((t0_)+j)*DI]; \
    P_##_u[j]  = bf2f(ubp[(size_t)((t0_)+j)*DI]); \
    P_##_B[j]  = *(const u16x4*)(Bp + (size_t)((t0_)+j)*XS); \
    P_##_C[j]  = *(const u16x4*)(Cp + (size_t)((t0_)+j)*XS); } }

#define SSTEP(P_, j, idx) { \
    const float dtu = P_##_dt[j] * P_##_u[j]; \
    h0 = fmaf(h0, __expf(P_##_dt[j] * Av[0]), dtu * bf2f(P_##_B[j][0])); \
    h1 = fmaf(h1, __expf(P_##_dt[j] * Av[1]), dtu * bf2f(P_##_B[j][1])); \
    h2 = fmaf(h2, __expf(P_##_dt[j] * Av[2]), dtu * bf2f(P_##_B[j][2])); \
    h3 = fmaf(h3, __expf(P_##_dt[j] * Av[3]), dtu * bf2f(P_##_B[j][3])); \
    float part = h0 * bf2f(P_##_C[j][0]); \
    part = fmaf(h1, bf2f(P_##_C[j][1]), part); \
    part = fmaf(h2, bf2f(P_##_C[j][2]), part); \
    part = fmaf(h3, bf2f(P_##_C[j][3]), part); \
    Pp[(idx)] = part; }

#define SCOMP(P_, base_) { \
    SSTEP(P_, 0, (base_)+0) SSTEP(P_, 1, (base_)+1) \
    SSTEP(P_, 2, (base_)+2) SSTEP(P_, 3, (base_)+3) }

__global__ __launch_bounds__(256) void scan_kernel(
    const float* __restrict__ delta, const __hip_bfloat16* __restrict__ ubf,
    const __hip_bfloat16* __restrict__ xz, const __hip_bfloat16* __restrict__ xdbc,
    const float* __restrict__ A_log, const float* __restrict__ D_ssm,
    __hip_bfloat16* __restrict__ y)
{
  const int wv = (int)((blockIdx.x * 256 + threadIdx.x) >> 6);   // 0..2047
  const int lane = threadIdx.x & 63;
  const int c = lane >> 4;
  const int s4 = lane & 15;
  const int g = (wv << 2) + c;        // global channel
  const int b = g >> 10;
  const int di = g & (DI - 1);
  float Av[4];
#pragma unroll
  for (int kk = 0; kk < 4; ++kk)
    Av[kk] = -__expf(A_log[di * SS + (s4 << 2) + kk]);
  const float Dd = D_ssm[di];
  const size_t rb = (size_t)b * LL;
  const float* __restrict__ dp = delta + rb * DI + di;
  const unsigned short* __restrict__ ubp = (const unsigned short*)ubf + rb * DI + di;
  const unsigned short* __restrict__ zbp = (const unsigned short*)xz + rb * ZSTR + DI + di;
  const unsigned short* __restrict__ Bp = (const unsigned short*)xdbc + rb * XS + RR + (s4 << 2);
  const unsigned short* __restrict__ Cp = Bp + SS;
  __hip_bfloat16* __restrict__ yp = y + rb * DI + di;

  float h0 = 0.f, h1 = 0.f, h2 = 0.f, h3 = 0.f;
  float Pp[16];
  float a_dt[4], a_u[4]; u16x4 a_B[4], a_C[4];
  float b_dt[4], b_u[4]; u16x4 b_B[4], b_C[4];
  float c_dt[4], c_u[4]; u16x4 c_B[4], c_C[4];
  float d_dt[4], d_u[4]; u16x4 d_B[4], d_C[4];

  float u_e = bf2f(ubp[(size_t)s4 * DI]);
  float z_e = bf2f(zbp[(size_t)s4 * ZSTR]);

  SLOAD(a, 0) SLOAD(b, 4) SLOAD(c, 8)
  for (int t0 = 0; t0 < LL; t0 += 16) {
    SLOAD(d, t0 + 12)
    SCOMP(a, 0)
    if (t0 + 16 < LL) SLOAD(a, t0 + 16)
    SCOMP(b, 4)
    float u_n = 0.f, z_n = 0.f;
    if (t0 + 16 < LL) {
      u_n = bf2f(ubp[(size_t)(t0 + 16 + s4) * DI]);
      z_n = bf2f(zbp[(size_t)(t0 + 16 + s4) * ZSTR]);
    }
    if (t0 + 20 < LL) SLOAD(b, t0 + 20)
    SCOMP(c, 8)
    if (t0 + 24 < LL) SLOAD(c, t0 + 24)
    SCOMP(d, 12)

    // butterfly reduce-scatter: lane s4 ends with total for step t0+s4
#pragma unroll
    for (int k2 = 0; k2 < 8; ++k2) {
      const float mn = (s4 & 1) ? Pp[2*k2+1] : Pp[2*k2];
      const float ot = (s4 & 1) ? Pp[2*k2]   : Pp[2*k2+1];
      Pp[k2] = mn + swz<0x041F>(ot);
    }
#pragma unroll
    for (int k2 = 0; k2 < 4; ++k2) {
      const float mn = (s4 & 2) ? Pp[2*k2+1] : Pp[2*k2];
      const float ot = (s4 & 2) ? Pp[2*k2]   : Pp[2*k2+1];
      Pp[k2] = mn + swz<0x081F>(ot);
    }
#pragma unroll
    for (int k2 = 0; k2 < 2; ++k2) {
      const float mn = (s4 & 4) ? Pp[2*k2+1] : Pp[2*k2];
      const float ot = (s4 & 4) ? Pp[2*k2]   : Pp[2*k2+1];
      Pp[k2] = mn + swz<0x101F>(ot);
    }
    {
      const float mn = (s4 & 8) ? Pp[1] : Pp[0];
      const float ot = (s4 & 8) ? Pp[0] : Pp[1];
      Pp[0] = mn + swz<0x201F>(ot);
    }

    const float yv = (Pp[0] + u_e * Dd) * (z_e / (1.f + __expf(-z_e)));
    yp[(size_t)(t0 + s4) * DI] = __float2bfloat16(yv);
    u_e = u_n; z_e = z_n;
  }
}

// ---------------------------------------------------------------------------
// MFMA flash attention. Block = 64 queries x one (b,h); 4 waves x 16 queries.
// qk: bf16 [B, L, 1024] (q cols 0..511, k cols 512..1023, head-sliced).
// vt: bf16 [B*H, 64 e, L keys]. Out: bf16 [B, L, 512].
// ---------------------------------------------------------------------------
__global__ __launch_bounds__(256) void attn_mfma(
    const __hip_bfloat16* __restrict__ qk,
    const __hip_bfloat16* __restrict__ vtg, __hip_bfloat16* __restrict__ og)
{
  __shared__ __align__(16) __hip_bfloat16 Qs[64][72];
  __shared__ __align__(16) __hip_bfloat16 Ks[64][72];
  __shared__ __align__(16) __hip_bfloat16 Vts[64][72];
  __shared__ __align__(16) __hip_bfloat16 Ps[4][16][72];
  const int tid = threadIdx.x;
  const int w = tid >> 6, lane = tid & 63;
  const int bh = blockIdx.y;
  const int b = bh >> 3, hh = bh & 7;
  const int q0 = blockIdx.x << 6;
  const size_t qbase = (size_t)b * LL * 1024 + (size_t)hh * EE;
  const size_t vtbase = (size_t)bh * EE * LL;
  const size_t obase = (size_t)b * LL * DD + (size_t)hh * EE;

  const int srow = tid >> 2, sch = (tid & 3) << 4;
  {
    const __hip_bfloat16* src = qk + qbase + (size_t)(q0 + srow) * 1024 + sch;
    *(uint4*)&Qs[srow][sch]     = *(const uint4*)src;
    *(uint4*)&Qs[srow][sch + 8] = *(const uint4*)(src + 8);
  }
  __syncthreads();

  const int fm = lane & 15;
  const int q8 = (lane >> 4) << 3;
  bf16x8 af0 = *(const bf16x8*)&Qs[w * 16 + fm][q8];
  bf16x8 af1 = *(const bf16x8*)&Qs[w * 16 + fm][32 + q8];

  f32x4 oacc[4];
  float m_i[4], l_i[4];
#pragma unroll
  for (int r = 0; r < 4; ++r) { m_i[r] = -INFINITY; l_i[r] = 0.f; }
#pragma unroll
  for (int j = 0; j < 4; ++j) oacc[j] = (f32x4){0.f, 0.f, 0.f, 0.f};

  for (int kt = 0; kt < LL / 64; ++kt) {
    const int k0 = kt << 6;
    __syncthreads();
    {
      const __hip_bfloat16* ksrc = qk + qbase + 512 + (size_t)(k0 + srow) * 1024 + sch;
      const __hip_bfloat16* vsrc = vtg + vtbase + (size_t)srow * LL + k0 + sch;
      *(uint4*)&Ks[srow][sch]      = *(const uint4*)ksrc;
      *(uint4*)&Ks[srow][sch + 8]  = *(const uint4*)(ksrc + 8);
      *(uint4*)&Vts[srow][sch]     = *(const uint4*)vsrc;
      *(uint4*)&Vts[srow][sch + 8] = *(const uint4*)(vsrc + 8);
    }
    __syncthreads();

    f32x4 sacc[4];
#pragma unroll
    for (int j = 0; j < 4; ++j) sacc[j] = (f32x4){0.f, 0.f, 0.f, 0.f};
#pragma unroll
    for (int j = 0; j < 4; ++j) {
      bf16x8 kf0 = *(const bf16x8*)&Ks[j * 16 + fm][q8];
      bf16x8 kf1 = *(const bf16x8*)&Ks[j * 16 + fm][32 + q8];
      sacc[j] = __builtin_amdgcn_mfma_f32_16x16x32_bf16(af0, kf0, sacc[j], 0, 0, 0);
      sacc[j] = __builtin_amdgcn_mfma_f32_16x16x32_bf16(af1, kf1, sacc[j], 0, 0, 0);
    }

    float alpha[4];
#pragma unroll
    for (int r = 0; r < 4; ++r) {
#pragma unroll
      for (int j = 0; j < 4; ++j) sacc[j][r] *= 0.125f;
      float mt = fmaxf(fmaxf(sacc[0][r], sacc[1][r]), fmaxf(sacc[2][r], sacc[3][r]));
      mt = fmaxf(mt, swz<0x041F>(mt)); mt = fmaxf(mt, swz<0x081F>(mt));
      mt = fmaxf(mt, swz<0x101F>(mt)); mt = fmaxf(mt, swz<0x201F>(mt));
      const float mn = fmaxf(m_i[r], mt);
      alpha[r] = __expf(m_i[r] - mn);
      m_i[r] = mn;
      float p[4], rs = 0.f;
#pragma unroll
      for (int j = 0; j < 4; ++j) { p[j] = __expf(sacc[j][r] - mn); rs += p[j]; }
      rs += swz<0x041F>(rs); rs += swz<0x081F>(rs);
      rs += swz<0x101F>(rs); rs += swz<0x201F>(rs);
      l_i[r] = l_i[r] * alpha[r] + rs;
      const int qrow = ((lane >> 4) << 2) + r;
#pragma unroll
      for (int j = 0; j < 4; ++j)
        Ps[w][qrow][j * 16 + fm] = __float2bfloat16(p[j]);
    }
#pragma unroll
    for (int j = 0; j < 4; ++j)
#pragma unroll
      for (int r = 0; r < 4; ++r) oacc[j][r] *= alpha[r];

    bf16x8 pf0 = *(const bf16x8*)&Ps[w][fm][q8];
    bf16x8 pf1 = *(const bf16x8*)&Ps[w][fm][32 + q8];
#pragma unroll
    for (int j = 0; j < 4; ++j) {
      bf16x8 v0 = *(const bf16x8*)&Vts[j * 16 + fm][q8];
      bf16x8 v1 = *(const bf16x8*)&Vts[j * 16 + fm][32 + q8];
      oacc[j] = __builtin_amdgcn_mfma_f32_16x16x32_bf16(pf0, v0, oacc[j], 0, 0, 0);
      oacc[j] = __builtin_amdgcn_mfma_f32_16x16x32_bf16(pf1, v1, oacc[j], 0, 0, 0);
    }
  }

#pragma unroll
  for (int r = 0; r < 4; ++r) {
    const float inv = 1.f / l_i[r];
    const int qq = q0 + w * 16 + ((lane >> 4) << 2) + r;
#pragma unroll
    for (int j = 0; j < 4; ++j)
      og[obase + (size_t)qq * DD + j * 16 + fm] = __float2bfloat16(oacc[j][r] * inv);
  }
}

// ---------------------------------------------------------------------------
// h = LN1(xf + attn + mamba); hn(bf16) = LN2(h).
// ---------------------------------------------------------------------------
__device__ __forceinline__ float block_sum512(float val, float* sm)
{
#pragma unroll
  for (int off = 32; off; off >>= 1) val += __shfl_xor(val, off, 64);
  const int wid = threadIdx.x >> 6;
  __syncthreads();
  if ((threadIdx.x & 63) == 0) sm[wid] = val;
  __syncthreads();
  return sm[0] + sm[1] + sm[2] + sm[3];
}

__global__ __launch_bounds__(256) void ln_fused(
    const float* __restrict__ xf, const float* __restrict__ ao,
    const float* __restrict__ mo,
    const float* __restrict__ g1, const float* __restrict__ b1,
    const float* __restrict__ g2, const float* __restrict__ b2,
    float* __restrict__ hout, __hip_bfloat16* __restrict__ hnout)
{
  __shared__ float sm[4];
  const size_t base = (size_t)blockIdx.x * DD;
  const int t = threadIdx.x;
  const float v0 = xf[base + t] + ao[base + t] + mo[base + t];
  const float v1 = xf[base + 256 + t] + ao[base + 256 + t] + mo[base + 256 + t];
  const float mean = block_sum512(v0 + v1, sm) * (1.f / DD);
  const float d0 = v0 - mean, d1 = v1 - mean;
  const float var = block_sum512(d0 * d0 + d1 * d1, sm) * (1.f / DD);
  const float rstd = rsqrtf(var + 1e-5f);
  const float h0 = d0 * rstd * g1[t] + b1[t];
  const float h1 = d1 * rstd * g1[t + 256] + b1[t + 256];
  hout[base + t] = h0;
  hout[base + 256 + t] = h1;
  const float mean2 = block_sum512(h0 + h1, sm) * (1.f / DD);
  const float e0 = h0 - mean2, e1 = h1 - mean2;
  const float var2 = block_sum512(e0 * e0 + e1 * e1, sm) * (1.f / DD);
  const float rstd2 = rsqrtf(var2 + 1e-6f);
  hnout[base + t] = __float2bfloat16(e0 * rstd2 * g2[t] + b2[t]);
  hnout[base + 256 + t] = __float2bfloat16(e1 * rstd2 * g2[t + 256] + b2[t + 256]);
}

// ---------------------------------------------------------------------------
extern "C" void kernel_launch(void* const* d_in, const int* in_sizes, int n_in,
                              void* d_out, int out_size, void* d_ws, size_t ws_size,
                              hipStream_t stream)
{
  const float* x         = (const float*)d_in[0];
  const float* Wq        = (const float*)d_in[2];
  const float* bq        = (const float*)d_in[3];
  const float* Wk        = (const float*)d_in[4];
  const float* bk        = (const float*)d_in[5];
  const float* Wv        = (const float*)d_in[6];
  const float* bv        = (const float*)d_in[7];
  const float* Wo        = (const float*)d_in[8];
  const float* bo        = (const float*)d_in[9];
  const float* in_proj_w = (const float*)d_in[10];
  const float* conv_w    = (const float*)d_in[11];
  const float* conv_b    = (const float*)d_in[12];
  const float* x_proj_w  = (const float*)d_in[13];
  const float* dt_proj_w = (const float*)d_in[14];
  const float* dt_proj_b = (const float*)d_in[15];
  const float* A_log     = (const float*)d_in[16];
  const float* D_ssm     = (const float*)d_in[17];
  const float* out_proj_w= (const float*)d_in[18];
  const float* ln1_g     = (const float*)d_in[19];
  const float* ln1_b     = (const float*)d_in[20];
  const float* ffn_w1    = (const float*)d_in[21];
  const float* ffn_b1    = (const float*)d_in[22];
  const float* ffn_w2    = (const float*)d_in[23];
  const float* ffn_b2    = (const float*)d_in[24];
  const float* ln2_g     = (const float*)d_in[25];
  const float* ln2_b     = (const float*)d_in[26];
  float* out = (float*)d_out;

  // ---- workspace layout (f32-unit offsets), peak ~136 MB
  // Weight arena needs w_f2 + 1048576 = 5,013,504 bf16 = 2,506,752 f32 units.
  float* ws = (float*)d_ws;
  const size_t OF_XBF = 2506752;               // xbf bf16 | later hnbf
  const size_t OF_XZ  = OF_XBF + 2359296;      // xz bf16 [ML,2048] | later qkbuf+vtbf
  const size_t OF_UBF = OF_XZ + 9437184;       // ubf bf16 | later aobuf f32
  const size_t OF_XD  = OF_UBF + 4718592;      // xdbc bf16
  const size_t OF_DF  = OF_XD + 737280;        // deltab f32 | attnbf+mambab | ffbf
  const size_t OF_YB  = OF_DF + 9437184;       // ybf bf16 | later hbuf f32
  const size_t OF_QB  = OF_YB + 4718592;       // qkv bias f32 [1536]

  __hip_bfloat16* wbf     = (__hip_bfloat16*)ws;
  __hip_bfloat16* xbf     = (__hip_bfloat16*)(ws + OF_XBF);
  __hip_bfloat16* hnbf    = (__hip_bfloat16*)(ws + OF_XBF);
  __hip_bfloat16* xz      = (__hip_bfloat16*)(ws + OF_XZ);
  __hip_bfloat16* qkbuf   = (__hip_bfloat16*)(ws + OF_XZ);
  __hip_bfloat16* vtbf    = (__hip_bfloat16*)(ws + OF_XZ + 4718592);
  __hip_bfloat16* ubf     = (__hip_bfloat16*)(ws + OF_UBF);
  float*          aobuf   = ws + OF_UBF;
  __hip_bfloat16* xdbc_bf = (__hip_bfloat16*)(ws + OF_XD);
  float*          deltab  = ws + OF_DF;
  __hip_bfloat16* attnbf  = (__hip_bfloat16*)(ws + OF_DF);
  float*          mambab  = ws + OF_DF + 2359296;
  __hip_bfloat16* ffbf    = (__hip_bfloat16*)(ws + OF_DF);
  __hip_bfloat16* ybf     = (__hip_bfloat16*)(ws + OF_YB);
  float*          hbuf    = ws + OF_YB;
  float*          qkvbias = ws + OF_QB;

  // weight offsets (bf16 elements) in wbf
  const size_t w_inproj = 0;
  const size_t w_xproj  = 1048576;    // rows padded 160->256
  const size_t w_dt     = 1310720;
  const size_t w_out    = 1343488;
  const size_t w_q      = 1867776;    // q,k,v contiguous -> 1536-row block
  const size_t w_o      = 2654208;
  const size_t w_f1     = 2916352;
  const size_t w_f2     = 3964928;

  const dim3 thr(256);
#define CVT(src, dst, n) cvt_bf16<<<dim3(((n)/4 + 255)/256), thr, 0, stream>>>(src, dst, n)
#define GEMM(Abf, lda_, Woff, Bptr, Rptr, Cptr, C2ptr, N_, K_, act_, md_) \
  gemm_mfma<<<dim3((N_ + 127)/128, ML/128), thr, 0, stream>>>( \
      Abf, lda_, wbf + (Woff), Bptr, Rptr, (void*)(Cptr), (void*)(C2ptr), ML, N_, K_, act_, md_)

  hipMemsetAsync((void*)(wbf + w_xproj + (size_t)160 * 1024), 0, (size_t)96 * 1024 * 2, stream);
  CVT(in_proj_w, wbf + w_inproj, 1048576);
  CVT(x_proj_w,  wbf + w_xproj,  163840);
  CVT(dt_proj_w, wbf + w_dt,     32768);
  CVT(out_proj_w,wbf + w_out,    524288);
  CVT(Wq,        wbf + w_q,           262144);
  CVT(Wk,        wbf + w_q + 262144,  262144);
  CVT(Wv,        wbf + w_q + 524288,  262144);
  CVT(Wo,        wbf + w_o,      262144);
  CVT(ffn_w1,    wbf + w_f1,     1048576);
  CVT(ffn_w2,    wbf + w_f2,     1048576);
  CVT(x,         xbf,            ML * DD);
  hipMemcpyAsync(qkvbias,        bq, 512 * sizeof(float), hipMemcpyDeviceToDevice, stream);
  hipMemcpyAsync(qkvbias + 512,  bk, 512 * sizeof(float), hipMemcpyDeviceToDevice, stream);
  hipMemcpyAsync(qkvbias + 1024, bv, 512 * sizeof(float), hipMemcpyDeviceToDevice, stream);

  // ---- mamba branch
  GEMM(xbf, DD, w_inproj, nullptr, nullptr, xz, nullptr, 2 * DI, DD, 0, 1);
  conv_silu<<<dim3((ML * DI) / 256), thr, 0, stream>>>(xz, conv_w, conv_b, ubf);
  GEMM(ubf, DI, w_xproj, nullptr, nullptr, xdbc_bf, nullptr, XS, DI, 0, 1);
  GEMM(xdbc_bf, XS, w_dt, dt_proj_b, nullptr, deltab, nullptr, DI, RR, 2, 0);
  scan_kernel<<<dim3(512), thr, 0, stream>>>(
      deltab, ubf, xz, xdbc_bf, A_log, D_ssm, ybf);
  GEMM(ybf, DI, w_out, nullptr, nullptr, mambab, nullptr, DD, DI, 0, 0);

  // ---- attention branch (qkv fused; qk/vt reuse xz region after scan)
  GEMM(xbf, DD, w_q, qkvbias, nullptr, qkbuf, vtbf, 3 * DD, DD, 0, 3);
  attn_mfma<<<dim3(LL / 64, BB * HH), thr, 0, stream>>>(qkbuf, vtbf, attnbf);
  GEMM(attnbf, DD, w_o, bo, nullptr, aobuf, nullptr, DD, DD, 0, 0);

  // ---- combine + LN1 + LN2
  ln_fused<<<dim3(ML), thr, 0, stream>>>(x, aobuf, mambab, ln1_g, ln1_b,
                                         ln2_g, ln2_b, hbuf, hnbf);

  // ---- FFN
  GEMM(hnbf, DD, w_f1, ffn_b1, nullptr, ffbf, nullptr, DFF, DD, 1, 1);
  GEMM(ffbf, DFF, w_f2, ffn_b2, hbuf, out, nullptr, DD, DFF, 0, 0);
#undef GEMM
#undef CVT
}

// Round 8
// 1036.216 us; speedup vs baseline: 3.3148x; 1.0061x over previous
//
#include <hip/hip_runtime.h>
#include <hip/hip_bf16.h>
#include <math.h>

#define BB 8
#define DD 512
#define HH 8
#define EE 64
#define DI 1024
#define SS 64
#define RR 32
#define KCONV 4
#define DFF 2048
#define LL 1152
#define ML (BB*LL)        // 9216
#define XS (RR + 2*SS)    // 160
#define ZSTR 2048
#define YSTR 1536         // concat [y | attn] row stride

typedef short bf16x8 __attribute__((ext_vector_type(8)));
typedef float f32x4 __attribute__((ext_vector_type(4)));
typedef unsigned short u16x4 __attribute__((ext_vector_type(4)));

#define GLD_LDS(g, l) \
  __builtin_amdgcn_global_load_lds((const __attribute__((address_space(1))) void*)(g), \
                                   (__attribute__((address_space(3))) void*)(l), 16, 0, 0)

__device__ __forceinline__ float bf2f(unsigned short u) {
  return __uint_as_float(((unsigned)u) << 16);
}

template<int IMM>
__device__ __forceinline__ float swz(float x) {
  return __uint_as_float((unsigned)__builtin_amdgcn_ds_swizzle((int)__float_as_uint(x), IMM));
}

// ---------------------------------------------------------------------------
// f32 -> bf16 conversion (contiguous)
// ---------------------------------------------------------------------------
__global__ __launch_bounds__(256) void cvt_bf16(
    const float* __restrict__ s, __hip_bfloat16* __restrict__ d, int n)
{
  const int i = (blockIdx.x * 256 + threadIdx.x) * 4;
  if (i + 3 < n) {
    const float4 v = *(const float4*)(s + i);
    __hip_bfloat16 t[4] = {__float2bfloat16(v.x), __float2bfloat16(v.y),
                           __float2bfloat16(v.z), __float2bfloat16(v.w)};
    *(ushort4*)(d + i) = *(const ushort4*)t;
  } else {
    for (int k = i; k < n; ++k) d[k] = __float2bfloat16(s[k]);
  }
}

// f32 -> bf16 with row repack: d[r*dststride + dstoff + c] = s[r*srclen + c]
__global__ __launch_bounds__(256) void cvt_pack(
    const float* __restrict__ s, __hip_bfloat16* __restrict__ d,
    int srclen, int dststride, int dstoff, int total)
{
  const int i = blockIdx.x * 256 + threadIdx.x;
  if (i >= total) return;
  const int r = i / srclen, c = i - r * srclen;
  d[(size_t)r * dststride + dstoff + c] = __float2bfloat16(s[i]);
}

// ---------------------------------------------------------------------------
// MFMA GEMM: C[m,n] = act( sum_k A[m,k]*W[n,k] + bias[n] ) + res[m,n]
// mode: 0 = f32 out; 1 = bf16 out; 3 = qkv split: n<1024 -> Cv[m*1024+n]
//       (bf16), n>=1024 -> V^T-per-head scatter into Cv2 [B*H, 64e, L].
// ---------------------------------------------------------------------------
__global__ __launch_bounds__(256) void gemm_mfma(
    const __hip_bfloat16* __restrict__ A, int lda,
    const __hip_bfloat16* __restrict__ W,
    const float* __restrict__ bias,
    const float* __restrict__ res,
    void* __restrict__ Cv, void* __restrict__ Cv2,
    int M, int N, int K, int act, int mode)
{
  __shared__ __align__(16) __hip_bfloat16 As[128 * 32];
  __shared__ __align__(16) __hip_bfloat16 Ws[128 * 32];
  const int tid = threadIdx.x;
  const int wid = tid >> 6, lane = tid & 63;
  const int wr = wid >> 1, wc = wid & 1;
  const int m0 = blockIdx.y << 7, n0 = blockIdx.x << 7;
  const int r1 = tid >> 2;
  const int c1 = (tid & 3) << 3;

  const __hip_bfloat16* ga0 = A + (size_t)(m0 + r1) * lda + c1;
  const __hip_bfloat16* ga1 = A + (size_t)(m0 + 64 + r1) * lda + c1;
  const __hip_bfloat16* gw0 = W + (size_t)(n0 + r1) * K + c1;
  const __hip_bfloat16* gw1 = W + (size_t)(n0 + 64 + r1) * K + c1;
  char* lA0 = (char*)As + wid * 1024;
  char* lA1 = lA0 + 4096;
  char* lW0 = (char*)Ws + wid * 1024;
  char* lW1 = lW0 + 4096;

  f32x4 acc[4][4];
#pragma unroll
  for (int i = 0; i < 4; ++i)
#pragma unroll
    for (int j = 0; j < 4; ++j) acc[i][j] = (f32x4){0.f, 0.f, 0.f, 0.f};

  const int fm = lane & 15;
  const int q8 = (lane >> 4) << 3;

  for (int kt = 0; kt < K; kt += 32) {
    __syncthreads();
    GLD_LDS(ga0, lA0); GLD_LDS(ga1, lA1);
    GLD_LDS(gw0, lW0); GLD_LDS(gw1, lW1);
    ga0 += 32; ga1 += 32; gw0 += 32; gw1 += 32;
    __syncthreads();

    bf16x8 af[4], wf[4];
#pragma unroll
    for (int i = 0; i < 4; ++i)
      af[i] = *(const bf16x8*)((const short*)As + (wr * 64 + i * 16 + fm) * 32 + q8);
#pragma unroll
    for (int j = 0; j < 4; ++j)
      wf[j] = *(const bf16x8*)((const short*)Ws + (wc * 64 + j * 16 + fm) * 32 + q8);
#pragma unroll
    for (int i = 0; i < 4; ++i)
#pragma unroll
      for (int j = 0; j < 4; ++j)
        acc[i][j] = __builtin_amdgcn_mfma_f32_16x16x32_bf16(af[i], wf[j], acc[i][j], 0, 0, 0);
  }

  const int rquad = (lane >> 4) << 2;
#pragma unroll
  for (int j = 0; j < 4; ++j) {
    const int n = n0 + wc * 64 + j * 16 + fm;
    if (n < N) {
      const float bv = bias ? bias[n] : 0.f;
#pragma unroll
      for (int i = 0; i < 4; ++i) {
        const int mb = m0 + wr * 64 + i * 16 + rquad;
#pragma unroll
        for (int r = 0; r < 4; ++r) {
          const int m = mb + r;
          float v = acc[i][j][r] + bv;
          if (act == 1) v = 0.5f * v * (1.f + erff(v * 0.70710678118654752f));
          else if (act == 2) v = fmaxf(v, 0.f) + log1pf(expf(-fabsf(v)));
          if (mode == 3) {
            if (n < 1024) {
              ((__hip_bfloat16*)Cv)[(size_t)m * 1024 + n] = __float2bfloat16(v);
            } else {
              const int e = n - 1024;
              const int bb2 = m / LL;
              const int key = m - bb2 * LL;
              ((__hip_bfloat16*)Cv2)[((size_t)(bb2 * HH + (e >> 6)) * EE + (e & 63)) * LL + key] =
                  __float2bfloat16(v);
            }
          } else {
            const size_t off = (size_t)m * N + n;
            if (res) v += res[off];
            if (mode == 1) ((__hip_bfloat16*)Cv)[off] = __float2bfloat16(v);
            else ((float*)Cv)[off] = v;
          }
        }
      }
    }
  }
}

// ---------------------------------------------------------------------------
// Causal depthwise conv1d (kernel 4) + SiLU.
// Input: interleaved in_proj output xz [ML, 2048] (u = cols 0..1023).
// ---------------------------------------------------------------------------
__global__ __launch_bounds__(256) void conv_silu(
    const __hip_bfloat16* __restrict__ xz, const float* __restrict__ cw,
    const float* __restrict__ cb, __hip_bfloat16* __restrict__ uout)
{
  const size_t idx = (size_t)blockIdx.x * 256 + threadIdx.x;
  if (idx >= (size_t)ML * DI) return;
  const int di = (int)(idx & (DI - 1));
  const int row = (int)(idx >> 10);
  const int t = row % LL;
  float acc = cb[di];
#pragma unroll
  for (int k = 0; k < KCONV; ++k) {
    if (t - (KCONV - 1) + k >= 0)
      acc = fmaf((float)xz[(size_t)(row - (KCONV - 1 - k)) * ZSTR + di],
                 cw[di * KCONV + k], acc);
  }
  uout[idx] = __float2bfloat16(acc / (1.f + __expf(-acc)));
}

// ---------------------------------------------------------------------------
// Fused scan + attention fat kernel.
//   blocks [0, 512):    selective-scan v5 (4 states/lane, 16 lanes/chan,
//                       4 chan/wave; butterfly reduce-scatter per 16-step
//                       frame; 4-tile ring prefetch). Writes yattn cols 0..1023.
//   blocks [512, 1664): MFMA flash attention (64-query tile per block).
//                       Writes yattn cols 1024..1535.
// Independent inputs/outputs; no inter-path sync.
// ---------------------------------------------------------------------------
#define SLOAD(P_, t0_) { _Pragma("unroll") for (int j = 0; j < 4; ++j) { \
    P_##_dt[j] = bf2f(dp[(size_t)((t0_)+j)*DI]); \
    P_##_u[j]  = bf2f(ubp[(size_t)((t0_)+j)*DI]); \
    P_##_B[j]  = *(const u16x4*)(Bp + (size_t)((t0_)+j)*XS); \
    P_##_C[j]  = *(const u16x4*)(Cp + (size_t)((t0_)+j)*XS); } }

#define SSTEP(P_, j, idx) { \
    const float dtu = P_##_dt[j] * P_##_u[j]; \
    h0 = fmaf(h0, __expf(P_##_dt[j] * Av[0]), dtu * bf2f(P_##_B[j][0])); \
    h1 = fmaf(h1, __expf(P_##_dt[j] * Av[1]), dtu * bf2f(P_##_B[j][1])); \
    h2 = fmaf(h2, __expf(P_##_dt[j] * Av[2]), dtu * bf2f(P_##_B[j][2])); \
    h3 = fmaf(h3, __expf(P_##_dt[j] * Av[3]), dtu * bf2f(P_##_B[j][3])); \
    float part = h0 * bf2f(P_##_C[j][0]); \
    part = fmaf(h1, bf2f(P_##_C[j][1]), part); \
    part = fmaf(h2, bf2f(P_##_C[j][2]), part); \
    part = fmaf(h3, bf2f(P_##_C[j][3]), part); \
    Pp[(idx)] = part; }

#define SCOMP(P_, base_) { \
    SSTEP(P_, 0, (base_)+0) SSTEP(P_, 1, (base_)+1) \
    SSTEP(P_, 2, (base_)+2) SSTEP(P_, 3, (base_)+3) }

__global__ __launch_bounds__(256) void scan_attn(
    const __hip_bfloat16* __restrict__ delta, const __hip_bfloat16* __restrict__ ubf,
    const __hip_bfloat16* __restrict__ xz, const __hip_bfloat16* __restrict__ xdbc,
    const float* __restrict__ A_log, const float* __restrict__ D_ssm,
    const __hip_bfloat16* __restrict__ qk, const __hip_bfloat16* __restrict__ vtg,
    __hip_bfloat16* __restrict__ yattn)
{
  __shared__ __align__(16) __hip_bfloat16 Qs[64][72];
  __shared__ __align__(16) __hip_bfloat16 Ks[64][72];
  __shared__ __align__(16) __hip_bfloat16 Vts[64][72];
  __shared__ __align__(16) __hip_bfloat16 Ps[4][16][72];
  const int tid = threadIdx.x;

  if (blockIdx.x < 512) {
    // ---------------- scan path ----------------
    const int wv = (int)((blockIdx.x * 256 + tid) >> 6);   // 0..2047
    const int lane = tid & 63;
    const int c = lane >> 4;
    const int s4 = lane & 15;
    const int g = (wv << 2) + c;
    const int b = g >> 10;
    const int di = g & (DI - 1);
    float Av[4];
#pragma unroll
    for (int kk = 0; kk < 4; ++kk)
      Av[kk] = -__expf(A_log[di * SS + (s4 << 2) + kk]);
    const float Dd = D_ssm[di];
    const size_t rb = (size_t)b * LL;
    const unsigned short* __restrict__ dp = (const unsigned short*)delta + rb * DI + di;
    const unsigned short* __restrict__ ubp = (const unsigned short*)ubf + rb * DI + di;
    const unsigned short* __restrict__ zbp = (const unsigned short*)xz + rb * ZSTR + DI + di;
    const unsigned short* __restrict__ Bp = (const unsigned short*)xdbc + rb * XS + RR + (s4 << 2);
    const unsigned short* __restrict__ Cp = Bp + SS;
    __hip_bfloat16* __restrict__ yp = yattn + rb * YSTR + di;

    float h0 = 0.f, h1 = 0.f, h2 = 0.f, h3 = 0.f;
    float Pp[16];
    float a_dt[4], a_u[4]; u16x4 a_B[4], a_C[4];
    float b_dt[4], b_u[4]; u16x4 b_B[4], b_C[4];
    float c_dt[4], c_u[4]; u16x4 c_B[4], c_C[4];
    float d_dt[4], d_u[4]; u16x4 d_B[4], d_C[4];

    float u_e = bf2f(ubp[(size_t)s4 * DI]);
    float z_e = bf2f(zbp[(size_t)s4 * ZSTR]);

    SLOAD(a, 0) SLOAD(b, 4) SLOAD(c, 8)
    for (int t0 = 0; t0 < LL; t0 += 16) {
      SLOAD(d, t0 + 12)
      SCOMP(a, 0)
      if (t0 + 16 < LL) SLOAD(a, t0 + 16)
      SCOMP(b, 4)
      float u_n = 0.f, z_n = 0.f;
      if (t0 + 16 < LL) {
        u_n = bf2f(ubp[(size_t)(t0 + 16 + s4) * DI]);
        z_n = bf2f(zbp[(size_t)(t0 + 16 + s4) * ZSTR]);
      }
      if (t0 + 20 < LL) SLOAD(b, t0 + 20)
      SCOMP(c, 8)
      if (t0 + 24 < LL) SLOAD(c, t0 + 24)
      SCOMP(d, 12)

#pragma unroll
      for (int k2 = 0; k2 < 8; ++k2) {
        const float mn = (s4 & 1) ? Pp[2*k2+1] : Pp[2*k2];
        const float ot = (s4 & 1) ? Pp[2*k2]   : Pp[2*k2+1];
        Pp[k2] = mn + swz<0x041F>(ot);
      }
#pragma unroll
      for (int k2 = 0; k2 < 4; ++k2) {
        const float mn = (s4 & 2) ? Pp[2*k2+1] : Pp[2*k2];
        const float ot = (s4 & 2) ? Pp[2*k2]   : Pp[2*k2+1];
        Pp[k2] = mn + swz<0x081F>(ot);
      }
#pragma unroll
      for (int k2 = 0; k2 < 2; ++k2) {
        const float mn = (s4 & 4) ? Pp[2*k2+1] : Pp[2*k2];
        const float ot = (s4 & 4) ? Pp[2*k2]   : Pp[2*k2+1];
        Pp[k2] = mn + swz<0x101F>(ot);
      }
      {
        const float mn = (s4 & 8) ? Pp[1] : Pp[0];
        const float ot = (s4 & 8) ? Pp[0] : Pp[1];
        Pp[0] = mn + swz<0x201F>(ot);
      }

      const float yv = (Pp[0] + u_e * Dd) * (z_e / (1.f + __expf(-z_e)));
      yp[(size_t)(t0 + s4) * YSTR] = __float2bfloat16(yv);
      u_e = u_n; z_e = z_n;
    }
    return;
  }

  // ---------------- attention path ----------------
  const int abid = blockIdx.x - 512;
  const int w = tid >> 6, lane = tid & 63;
  const int bh = abid / (LL / 64);
  const int qtile = abid - bh * (LL / 64);
  const int b = bh >> 3, hh = bh & 7;
  const int q0 = qtile << 6;
  const size_t qbase = (size_t)b * LL * 1024 + (size_t)hh * EE;
  const size_t vtbase = (size_t)bh * EE * LL;

  const int srow = tid >> 2, sch = (tid & 3) << 4;
  {
    const __hip_bfloat16* src = qk + qbase + (size_t)(q0 + srow) * 1024 + sch;
    *(uint4*)&Qs[srow][sch]     = *(const uint4*)src;
    *(uint4*)&Qs[srow][sch + 8] = *(const uint4*)(src + 8);
  }
  __syncthreads();

  const int fm = lane & 15;
  const int q8 = (lane >> 4) << 3;
  bf16x8 af0 = *(const bf16x8*)&Qs[w * 16 + fm][q8];
  bf16x8 af1 = *(const bf16x8*)&Qs[w * 16 + fm][32 + q8];

  f32x4 oacc[4];
  float m_i[4], l_i[4];
#pragma unroll
  for (int r = 0; r < 4; ++r) { m_i[r] = -INFINITY; l_i[r] = 0.f; }
#pragma unroll
  for (int j = 0; j < 4; ++j) oacc[j] = (f32x4){0.f, 0.f, 0.f, 0.f};

  for (int kt = 0; kt < LL / 64; ++kt) {
    const int k0 = kt << 6;
    __syncthreads();
    {
      const __hip_bfloat16* ksrc = qk + qbase + 512 + (size_t)(k0 + srow) * 1024 + sch;
      const __hip_bfloat16* vsrc = vtg + vtbase + (size_t)srow * LL + k0 + sch;
      *(uint4*)&Ks[srow][sch]      = *(const uint4*)ksrc;
      *(uint4*)&Ks[srow][sch + 8]  = *(const uint4*)(ksrc + 8);
      *(uint4*)&Vts[srow][sch]     = *(const uint4*)vsrc;
      *(uint4*)&Vts[srow][sch + 8] = *(const uint4*)(vsrc + 8);
    }
    __syncthreads();

    f32x4 sacc[4];
#pragma unroll
    for (int j = 0; j < 4; ++j) sacc[j] = (f32x4){0.f, 0.f, 0.f, 0.f};
#pragma unroll
    for (int j = 0; j < 4; ++j) {
      bf16x8 kf0 = *(const bf16x8*)&Ks[j * 16 + fm][q8];
      bf16x8 kf1 = *(const bf16x8*)&Ks[j * 16 + fm][32 + q8];
      sacc[j] = __builtin_amdgcn_mfma_f32_16x16x32_bf16(af0, kf0, sacc[j], 0, 0, 0);
      sacc[j] = __builtin_amdgcn_mfma_f32_16x16x32_bf16(af1, kf1, sacc[j], 0, 0, 0);
    }

    float alpha[4];
#pragma unroll
    for (int r = 0; r < 4; ++r) {
#pragma unroll
      for (int j = 0; j < 4; ++j) sacc[j][r] *= 0.125f;
      float mt = fmaxf(fmaxf(sacc[0][r], sacc[1][r]), fmaxf(sacc[2][r], sacc[3][r]));
      mt = fmaxf(mt, swz<0x041F>(mt)); mt = fmaxf(mt, swz<0x081F>(mt));
      mt = fmaxf(mt, swz<0x101F>(mt)); mt = fmaxf(mt, swz<0x201F>(mt));
      const float mn = fmaxf(m_i[r], mt);
      alpha[r] = __expf(m_i[r] - mn);
      m_i[r] = mn;
      float p[4], rs = 0.f;
#pragma unroll
      for (int j = 0; j < 4; ++j) { p[j] = __expf(sacc[j][r] - mn); rs += p[j]; }
      rs += swz<0x041F>(rs); rs += swz<0x081F>(rs);
      rs += swz<0x101F>(rs); rs += swz<0x201F>(rs);
      l_i[r] = l_i[r] * alpha[r] + rs;
      const int qrow = ((lane >> 4) << 2) + r;
#pragma unroll
      for (int j = 0; j < 4; ++j)
        Ps[w][qrow][j * 16 + fm] = __float2bfloat16(p[j]);
    }
#pragma unroll
    for (int j = 0; j < 4; ++j)
#pragma unroll
      for (int r = 0; r < 4; ++r) oacc[j][r] *= alpha[r];

    bf16x8 pf0 = *(const bf16x8*)&Ps[w][fm][q8];
    bf16x8 pf1 = *(const bf16x8*)&Ps[w][fm][32 + q8];
#pragma unroll
    for (int j = 0; j < 4; ++j) {
      bf16x8 v0 = *(const bf16x8*)&Vts[j * 16 + fm][q8];
      bf16x8 v1 = *(const bf16x8*)&Vts[j * 16 + fm][32 + q8];
      oacc[j] = __builtin_amdgcn_mfma_f32_16x16x32_bf16(pf0, v0, oacc[j], 0, 0, 0);
      oacc[j] = __builtin_amdgcn_mfma_f32_16x16x32_bf16(pf1, v1, oacc[j], 0, 0, 0);
    }
  }

#pragma unroll
  for (int r = 0; r < 4; ++r) {
    const float inv = 1.f / l_i[r];
    const int qq = q0 + w * 16 + ((lane >> 4) << 2) + r;
#pragma unroll
    for (int j = 0; j < 4; ++j)
      yattn[((size_t)b * LL + qq) * YSTR + 1024 + hh * EE + j * 16 + fm] =
          __float2bfloat16(oacc[j][r] * inv);
  }
}

// ---------------------------------------------------------------------------
// h = LN1(xf + combo); hn(bf16) = LN2(h).  combo = attn_out + mamba_out + bo.
// ---------------------------------------------------------------------------
__device__ __forceinline__ float block_sum512(float val, float* sm)
{
#pragma unroll
  for (int off = 32; off; off >>= 1) val += __shfl_xor(val, off, 64);
  const int wid = threadIdx.x >> 6;
  __syncthreads();
  if ((threadIdx.x & 63) == 0) sm[wid] = val;
  __syncthreads();
  return sm[0] + sm[1] + sm[2] + sm[3];
}

__global__ __launch_bounds__(256) void ln_fused(
    const float* __restrict__ xf, const float* __restrict__ combo,
    const float* __restrict__ g1, const float* __restrict__ b1,
    const float* __restrict__ g2, const float* __restrict__ b2,
    float* __restrict__ hout, __hip_bfloat16* __restrict__ hnout)
{
  __shared__ float sm[4];
  const size_t base = (size_t)blockIdx.x * DD;
  const int t = threadIdx.x;
  const float v0 = xf[base + t] + combo[base + t];
  const float v1 = xf[base + 256 + t] + combo[base + 256 + t];
  const float mean = block_sum512(v0 + v1, sm) * (1.f / DD);
  const float d0 = v0 - mean, d1 = v1 - mean;
  const float var = block_sum512(d0 * d0 + d1 * d1, sm) * (1.f / DD);
  const float rstd = rsqrtf(var + 1e-5f);
  const float h0 = d0 * rstd * g1[t] + b1[t];
  const float h1 = d1 * rstd * g1[t + 256] + b1[t + 256];
  hout[base + t] = h0;
  hout[base + 256 + t] = h1;
  const float mean2 = block_sum512(h0 + h1, sm) * (1.f / DD);
  const float e0 = h0 - mean2, e1 = h1 - mean2;
  const float var2 = block_sum512(e0 * e0 + e1 * e1, sm) * (1.f / DD);
  const float rstd2 = rsqrtf(var2 + 1e-6f);
  hnout[base + t] = __float2bfloat16(e0 * rstd2 * g2[t] + b2[t]);
  hnout[base + 256 + t] = __float2bfloat16(e1 * rstd2 * g2[t + 256] + b2[t + 256]);
}

// ---------------------------------------------------------------------------
extern "C" void kernel_launch(void* const* d_in, const int* in_sizes, int n_in,
                              void* d_out, int out_size, void* d_ws, size_t ws_size,
                              hipStream_t stream)
{
  const float* x         = (const float*)d_in[0];
  const float* Wq        = (const float*)d_in[2];
  const float* bq        = (const float*)d_in[3];
  const float* Wk        = (const float*)d_in[4];
  const float* bk        = (const float*)d_in[5];
  const float* Wv        = (const float*)d_in[6];
  const float* bv        = (const float*)d_in[7];
  const float* Wo        = (const float*)d_in[8];
  const float* bo        = (const float*)d_in[9];
  const float* in_proj_w = (const float*)d_in[10];
  const float* conv_w    = (const float*)d_in[11];
  const float* conv_b    = (const float*)d_in[12];
  const float* x_proj_w  = (const float*)d_in[13];
  const float* dt_proj_w = (const float*)d_in[14];
  const float* dt_proj_b = (const float*)d_in[15];
  const float* A_log     = (const float*)d_in[16];
  const float* D_ssm     = (const float*)d_in[17];
  const float* out_proj_w= (const float*)d_in[18];
  const float* ln1_g     = (const float*)d_in[19];
  const float* ln1_b     = (const float*)d_in[20];
  const float* ffn_w1    = (const float*)d_in[21];
  const float* ffn_b1    = (const float*)d_in[22];
  const float* ffn_w2    = (const float*)d_in[23];
  const float* ffn_b2    = (const float*)d_in[24];
  const float* ln2_g     = (const float*)d_in[25];
  const float* ln2_b     = (const float*)d_in[26];
  float* out = (float*)d_out;

  // ---- workspace layout (f32-unit offsets), peak 154.5 MB
  float* ws = (float*)d_ws;
  const size_t OF_XBF = 2506752;               // xbf bf16 | later hnbf
  const size_t OF_XZ  = OF_XBF + 2359296;      // xz bf16 [ML,2048]
  const size_t OF_UBF = OF_XZ + 9437184;       // ubf bf16 | later combo f32
  const size_t OF_XD  = OF_UBF + 4718592;      // xdbc bf16
  const size_t OF_DF  = OF_XD + 737280;        // deltab bf16 | ffbf (part 1)
  const size_t OF_QKV = OF_DF + 4718592;       // qkbuf+vtbf bf16 | ffbf (part 2)
  const size_t OF_YA  = OF_QKV + 7077888;      // yattn bf16 [ML,1536] | later hbuf f32
  const size_t OF_QB  = OF_YA + 7077888;       // qkv bias f32 [1536]

  __hip_bfloat16* wbf     = (__hip_bfloat16*)ws;
  __hip_bfloat16* xbf     = (__hip_bfloat16*)(ws + OF_XBF);
  __hip_bfloat16* hnbf    = (__hip_bfloat16*)(ws + OF_XBF);
  __hip_bfloat16* xz      = (__hip_bfloat16*)(ws + OF_XZ);
  __hip_bfloat16* ubf     = (__hip_bfloat16*)(ws + OF_UBF);
  float*          combo   = ws + OF_UBF;
  __hip_bfloat16* xdbc_bf = (__hip_bfloat16*)(ws + OF_XD);
  __hip_bfloat16* deltab  = (__hip_bfloat16*)(ws + OF_DF);
  __hip_bfloat16* ffbf    = (__hip_bfloat16*)(ws + OF_DF);
  __hip_bfloat16* qkbuf   = (__hip_bfloat16*)(ws + OF_QKV);
  __hip_bfloat16* vtbf    = (__hip_bfloat16*)(ws + OF_QKV + 4718592);
  __hip_bfloat16* yattn   = (__hip_bfloat16*)(ws + OF_YA);
  float*          hbuf    = ws + OF_YA;
  float*          qkvbias = ws + OF_QB;

  // weight offsets (bf16 elements) in wbf
  const size_t w_inproj = 0;          // 1048576
  const size_t w_xproj  = 1048576;    // rows padded 160->256 (262144)
  const size_t w_dt     = 1310720;    // 32768
  const size_t w_cat    = 1343488;    // [512, 1536] = out_proj | Wo (786432)
  const size_t w_q      = 2129920;    // q,k,v contiguous 1536x512 (786432)
  const size_t w_f1     = 2916352;    // 1048576
  const size_t w_f2     = 3964928;    // 1048576; total 5013504 bf16

  const dim3 thr(256);
#define CVT(src, dst, n) cvt_bf16<<<dim3(((n)/4 + 255)/256), thr, 0, stream>>>(src, dst, n)
#define GEMM(Abf, lda_, Woff, Bptr, Rptr, Cptr, C2ptr, N_, K_, act_, md_) \
  gemm_mfma<<<dim3((N_ + 127)/128, ML/128), thr, 0, stream>>>( \
      Abf, lda_, wbf + (Woff), Bptr, Rptr, (void*)(Cptr), (void*)(C2ptr), ML, N_, K_, act_, md_)

  hipMemsetAsync((void*)(wbf + w_xproj + (size_t)160 * 1024), 0, (size_t)96 * 1024 * 2, stream);
  CVT(in_proj_w, wbf + w_inproj, 1048576);
  CVT(x_proj_w,  wbf + w_xproj,  163840);
  CVT(dt_proj_w, wbf + w_dt,     32768);
  cvt_pack<<<dim3((524288 + 255)/256), thr, 0, stream>>>(
      out_proj_w, wbf + w_cat, 1024, 1536, 0,    524288);
  cvt_pack<<<dim3((262144 + 255)/256), thr, 0, stream>>>(
      Wo,         wbf + w_cat, 512,  1536, 1024, 262144);
  CVT(Wq,        wbf + w_q,           262144);
  CVT(Wk,        wbf + w_q + 262144,  262144);
  CVT(Wv,        wbf + w_q + 524288,  262144);
  CVT(ffn_w1,    wbf + w_f1,    1048576);
  CVT(ffn_w2,    wbf + w_f2,    1048576);
  CVT(x,         xbf,           ML * DD);
  hipMemcpyAsync(qkvbias,        bq, 512 * sizeof(float), hipMemcpyDeviceToDevice, stream);
  hipMemcpyAsync(qkvbias + 512,  bk, 512 * sizeof(float), hipMemcpyDeviceToDevice, stream);
  hipMemcpyAsync(qkvbias + 1024, bv, 512 * sizeof(float), hipMemcpyDeviceToDevice, stream);

  // ---- mamba preprocessing
  GEMM(xbf, DD, w_inproj, nullptr, nullptr, xz, nullptr, 2 * DI, DD, 0, 1);
  conv_silu<<<dim3((ML * DI) / 256), thr, 0, stream>>>(xz, conv_w, conv_b, ubf);
  GEMM(ubf, DI, w_xproj, nullptr, nullptr, xdbc_bf, nullptr, XS, DI, 0, 1);
  GEMM(xdbc_bf, XS, w_dt, dt_proj_b, nullptr, deltab, nullptr, DI, RR, 2, 1);

  // ---- attention preprocessing (QKV fused)
  GEMM(xbf, DD, w_q, qkvbias, nullptr, qkbuf, vtbf, 3 * DD, DD, 0, 3);

  // ---- fused scan (512 blocks) + flash attention (1152 blocks)
  scan_attn<<<dim3(512 + BB * HH * (LL / 64)), thr, 0, stream>>>(
      deltab, ubf, xz, xdbc_bf, A_log, D_ssm, qkbuf, vtbf, yattn);

  // ---- combined output projection: combo = y@out_proj^T + attn@Wo^T + bo
  GEMM(yattn, YSTR, w_cat, bo, nullptr, combo, nullptr, DD, YSTR, 0, 0);

  // ---- combine + LN1 + LN2
  ln_fused<<<dim3(ML), thr, 0, stream>>>(x, combo, ln1_g, ln1_b,
                                         ln2_g, ln2_b, hbuf, hnbf);

  // ---- FFN
  GEMM(hnbf, DD, w_f1, ffn_b1, nullptr, ffbf, nullptr, DFF, DD, 1, 1);
  GEMM(ffbf, DFF, w_f2, ffn_b2, hbuf, out, nullptr, DD, DFF, 0, 0);
#undef GEMM
#undef CVT
}